// Round 3
// baseline (418.227 us; speedup 1.0000x reference)
//
#include <hip/hip_runtime.h>
#include <math.h>

#define HEADS   16
#define DHEAD   64
#define SEQ     2048
#define NB      2
#define DM      1024
#define NTOK    4096           // NB*SEQ
#define WEPS    1e-5

using f16x8   = __attribute__((ext_vector_type(8))) _Float16;
using f16x4   = __attribute__((ext_vector_type(4))) _Float16;
using floatx4 = __attribute__((ext_vector_type(4))) float;
using i32x4   = __attribute__((ext_vector_type(4))) int;

typedef __attribute__((address_space(1))) unsigned int gu32;
typedef __attribute__((address_space(3))) unsigned int lu32;

// lgkmcnt(0)-only barrier: does NOT drain vmcnt (register prefetch survives).
// Safe because LDS staging here is plain ds_write (not global_load_lds DMA).
#define BAR_LGKM()  asm volatile("s_waitcnt lgkmcnt(0)\n\ts_barrier" ::: "memory")
#define WAIT_LGKM() asm volatile("s_waitcnt lgkmcnt(0)" ::: "memory")

__device__ __forceinline__ unsigned short h16b(_Float16 h) {
    union { _Float16 h; unsigned short u; } c; c.h = h; return c.u;
}

// ---------------- weight |w| mean: pass 1 (partial sums in double) ----------------
__global__ void wsum1(const float* __restrict__ w0, const float* __restrict__ w1,
                      const float* __restrict__ w2, const float* __restrict__ w3,
                      double* __restrict__ partial) {
    const float* w = (blockIdx.y == 0) ? w0 : (blockIdx.y == 1) ? w1 : (blockIdx.y == 2) ? w2 : w3;
    int base = blockIdx.x * 16384;
    double s = 0.0;
    for (int i = threadIdx.x; i < 16384; i += 256)
        s += fabs((double)w[base + i]);
    __shared__ double sd[256];
    sd[threadIdx.x] = s;
    __syncthreads();
    for (int st = 128; st > 0; st >>= 1) {
        if (threadIdx.x < st) sd[threadIdx.x] += sd[threadIdx.x + st];
        __syncthreads();
    }
    if (threadIdx.x == 0) partial[blockIdx.y * 64 + blockIdx.x] = sd[0];
}

// ---------------- weight mean: pass 2 -> wscale[w] = clip(mean|w|, eps) ----------------
__global__ void wsum2(const double* __restrict__ partial, double* __restrict__ wscale) {
    int t = threadIdx.x;
    if (t < 4) {
        double s = 0.0;
        for (int i = 0; i < 64; i++) s += partial[t * 64 + i];
        double mean = s / (1024.0 * 1024.0);
        wscale[t] = (mean > WEPS) ? mean : WEPS;
    }
}

// ---------------- ternary weight quant -> int8 {-1,0,1} ----------------
__global__ void wquant(const float* __restrict__ w0, const float* __restrict__ w1,
                       const float* __restrict__ w2, const float* __restrict__ w3,
                       const double* __restrict__ wscale, signed char* __restrict__ wq) {
    int widx = blockIdx.y;
    const float* w = (widx == 0) ? w0 : (widx == 1) ? w1 : (widx == 2) ? w2 : w3;
    double ws = 1.0 / wscale[widx];
    int idx = (blockIdx.x * 256 + threadIdx.x) * 4;
    float4 wv = *(const float4*)(w + idx);
    char4 o;
    {
        double r = rint((double)wv.x * ws); r = r > 1.0 ? 1.0 : (r < -1.0 ? -1.0 : r); o.x = (signed char)r;
    } {
        double r = rint((double)wv.y * ws); r = r > 1.0 ? 1.0 : (r < -1.0 ? -1.0 : r); o.y = (signed char)r;
    } {
        double r = rint((double)wv.z * ws); r = r > 1.0 ? 1.0 : (r < -1.0 ? -1.0 : r); o.z = (signed char)r;
    } {
        double r = rint((double)wv.w * ws); r = r > 1.0 ? 1.0 : (r < -1.0 ? -1.0 : r); o.w = (signed char)r;
    }
    *(char4*)(wq + (size_t)widx * 1048576 + idx) = o;
}

// ---------------- per-token int8 absmax activation quant -> int8 ----------------
__device__ __forceinline__ void aquant_row(const float* __restrict__ row,
                                           signed char* __restrict__ dst_row,
                                           double* __restrict__ ascale_p) {
    int t = threadIdx.x;
    float4 xv = *(const float4*)(row + t * 4);
    float a = fmaxf(fmaxf(fabsf(xv.x), fabsf(xv.y)), fmaxf(fabsf(xv.z), fabsf(xv.w)));
    __shared__ float sm[256];
    sm[t] = a;
    __syncthreads();
    for (int st = 128; st > 0; st >>= 1) {
        if (t < st) sm[t] = fmaxf(sm[t], sm[t + st]);
        __syncthreads();
    }
    double mx = (double)sm[0];
    if (mx < WEPS) mx = WEPS;
    if (t == 0) *ascale_p = mx / 127.0;
    double xs = 127.0 / mx;
    char4 o;
    {
        double r = rint((double)xv.x * xs); r = r > 127.0 ? 127.0 : (r < -128.0 ? -128.0 : r); o.x = (signed char)r;
    } {
        double r = rint((double)xv.y * xs); r = r > 127.0 ? 127.0 : (r < -128.0 ? -128.0 : r); o.y = (signed char)r;
    } {
        double r = rint((double)xv.z * xs); r = r > 127.0 ? 127.0 : (r < -128.0 ? -128.0 : r); o.z = (signed char)r;
    } {
        double r = rint((double)xv.w * xs); r = r > 127.0 ? 127.0 : (r < -128.0 ? -128.0 : r); o.w = (signed char)r;
    }
    *(char4*)(dst_row + t * 4) = o;
}

__global__ void aquant(const float* __restrict__ src, signed char* __restrict__ dst,
                       double* __restrict__ ascale) {
    int tok = blockIdx.x;
    aquant_row(src + (size_t)tok * DM, dst + (size_t)tok * DM, ascale + tok);
}

// fused x + context quant: xq/cq and ascale_x/ascale_c are contiguous in ws
__global__ void aquant2(const float* __restrict__ x, const float* __restrict__ ctx,
                        signed char* __restrict__ dst, double* __restrict__ ascale) {
    int tok = blockIdx.x;
    const float* row = (tok < NTOK) ? x + (size_t)tok * DM : ctx + (size_t)(tok - NTOK) * DM;
    aquant_row(row, dst + (size_t)tok * DM, ascale + tok);
}

// ---------------- int8 MFMA GEMM core: C[m][n] = sum_k A[m][k]*W[n][k], exact i32 ----------
// m97 structure: async global_load_lds width-16 staging, 128x128 tile, BK=64.
// mode 0: write SEPARATE hi/lo f16 limb planes at [b][h][t][dh]
//         (hi = (f16)(val*prescale), lo = (f16)((v-hi)*2048); lo plane at +4194304 elems)
// mode 2: SEPARATE hi/lo f16 limb planes, V transposed [b][h][dh][t]
//         (lo plane at +4194304 elems). 4 consecutive t live in-lane (reg idx) ->
//         packed ushort4 b64 stores, 4x fewer store instrs than scattered 2B.
// mode 1: plain fp32 [t][o].
__device__ __forceinline__ void gemm_core(
        const signed char* __restrict__ A, const signed char* __restrict__ W,
        const double* __restrict__ ascale, double wsc,
        void* __restrict__ outp, int mode, float prescale, int bx, int by) {
    __shared__ __align__(16) signed char lds_a[128 * 64];
    __shared__ __align__(16) signed char lds_b[128 * 64];
    const int tid  = threadIdx.x;
    const int wave = tid >> 6, lane = tid & 63;
    const int wr = wave >> 1, wc = wave & 1;
    const int quad = lane >> 4, l15 = lane & 15;
    const int row0 = by * 128, col0 = bx * 128;
    i32x4 acc[4][4] = {};

    const signed char* ga0 = A + (size_t)(row0 + (lane >> 2)) * DM + (lane & 3) * 16;
    const signed char* gb0 = W + (size_t)(col0 + (lane >> 2)) * DM + (lane & 3) * 16;

    for (int k0 = 0; k0 < DM; k0 += 64) {
        __syncthreads();
        #pragma unroll
        for (int t = 0; t < 2; t++) {
            const int i = wave + t * 4;                 // wave-uniform instr index, 8 total
            __builtin_amdgcn_global_load_lds(
                (const gu32*)(const void*)(ga0 + (size_t)i * 16 * DM + k0),
                (lu32*)(void*)(lds_a + i * 1024), 16, 0, 0);
            __builtin_amdgcn_global_load_lds(
                (const gu32*)(const void*)(gb0 + (size_t)i * 16 * DM + k0),
                (lu32*)(void*)(lds_b + i * 1024), 16, 0, 0);
        }
        __syncthreads();
        i32x4 af[4], bfr[4];
        #pragma unroll
        for (int mi = 0; mi < 4; mi++) {
            int r = wr * 64 + mi * 16 + l15;
            af[mi] = *(const i32x4*)&lds_a[r * 64 + quad * 16];
        }
        #pragma unroll
        for (int ni = 0; ni < 4; ni++) {
            int n = wc * 64 + ni * 16 + l15;
            bfr[ni] = *(const i32x4*)&lds_b[n * 64 + quad * 16];
        }
        #pragma unroll
        for (int mi = 0; mi < 4; mi++)
            #pragma unroll
            for (int ni = 0; ni < 4; ni++)
                acc[mi][ni] = __builtin_amdgcn_mfma_i32_16x16x64_i8(af[mi], bfr[ni], acc[mi][ni], 0, 0, 0);
    }

    #pragma unroll
    for (int mi = 0; mi < 4; mi++) {
        int tbase = row0 + wr * 64 + mi * 16 + quad * 4;
        if (mode == 2) {
            int bb = tbase >> 11, n = tbase & 2047;
            #pragma unroll
            for (int ni = 0; ni < 4; ni++) {
                int o = col0 + wc * 64 + ni * 16 + l15;
                int hh = o >> 6, dh = o & 63;
                ushort4 hv, lv;
                #pragma unroll
                for (int reg = 0; reg < 4; reg++) {
                    int t = tbase + reg;
                    double sa = ascale[t] * wsc;
                    float fv = (float)((double)acc[mi][ni][reg] * sa) * prescale;
                    _Float16 hl = (_Float16)fv;
                    _Float16 ml = (_Float16)((fv - (float)hl) * 2048.0f);
                    ((unsigned short*)&hv)[reg] = h16b(hl);
                    ((unsigned short*)&lv)[reg] = h16b(ml);
                }
                size_t idx = (((size_t)(bb * HEADS + hh) * 64 + dh) << 11) + n;
                *(ushort4*)((unsigned short*)outp + idx)           = hv;
                *(ushort4*)((unsigned short*)outp + idx + 4194304) = lv;
            }
        } else {
            #pragma unroll
            for (int reg = 0; reg < 4; reg++) {
                int t = tbase + reg;
                double sa = ascale[t] * wsc;
                #pragma unroll
                for (int ni = 0; ni < 4; ni++) {
                    int o = col0 + wc * 64 + ni * 16 + l15;
                    float val = (float)((double)acc[mi][ni][reg] * sa);
                    if (mode == 1) {
                        ((float*)outp)[(size_t)t * DM + o] = val;
                    } else {
                        int bb = t >> 11, n = t & 2047, hh = o >> 6, dh = o & 63;
                        float fv = val * prescale;
                        _Float16 hl = (_Float16)fv;
                        _Float16 ml = (_Float16)((fv - (float)hl) * 2048.0f);
                        size_t idx = (((size_t)(bb * HEADS + hh) * SEQ + n) << 6) + dh;
                        ((unsigned short*)outp)[idx]           = h16b(hl);
                        ((unsigned short*)outp)[idx + 4194304] = h16b(ml);
                    }
                }
            }
        }
    }
}

// fused Q/K/V projections: 768 blocks = 3/CU co-resident (hides barrier drain)
// Q prescale folds softmax scale AND log2(e): 0.125 * 1.4426950408889634
__global__ __launch_bounds__(256) void gemm_qkv(
        const signed char* __restrict__ xq, const signed char* __restrict__ cq,
        const signed char* __restrict__ wqb, const double* __restrict__ ascale_x,
        const double* __restrict__ wscale, void* __restrict__ qkv) {
    const int which = blockIdx.x >> 3;          // 0=Q, 1=K, 2=V
    char* base = (char*)qkv + (size_t)which * 16777216;
    gemm_core(which == 0 ? xq : cq,
              wqb + (size_t)which * 1048576,
              ascale_x + (which ? NTOK : 0),
              wscale[which],
              base,
              which == 2 ? 2 : 0,
              which == 0 ? 0.18033688011112042f : 1.0f, blockIdx.x & 7, blockIdx.y);
}

__global__ __launch_bounds__(256) void gemm_o(
        const signed char* __restrict__ aq, const signed char* __restrict__ wo,
        const double* __restrict__ ascale, const double* __restrict__ wscale_p,
        float* __restrict__ out) {
    gemm_core(aq, wo, ascale, *wscale_p, out, 1, 1.0f, blockIdx.x, blockIdx.y);
}

// ---------------- MFMA flash attention v6: V direct from global, K via LDS ----------------
// v5 post-mortem: LDS pipe was ~84% utilized (K 8 + V 8 + P 2 b128 reads + staging per
// wave-tile ~ 280 cyc x 1024 wave-tiles/CU ~ 287K cyc of 340K) -- V through LDS traded
// idle HBM (3.4%) into the saturated LDS pipe. Fix: V B-fragments load STRAIGHT from the
// global limb planes ([b][h][dh][t] -> f16x8 at (dh<<11)+kt+quad*8, fragment-shaped, no
// unpack). LDS now carries only K + P (~164 cyc/wave-tile); V rides the vector-mem path
// (~64B/cyc/CU) -- two different pipes that overlap. V loads issue right after QK MFMAs;
// vmcnt-wait lands at PV, covered by softmax + P round-trip (WAIT_LGKM doesn't drain vmcnt).
// bh remap: co-resident blocks (lin, lin+256, ...) share bh -> identical K/V global
// addresses -> L1 absorbs the 4x intra-CU redundancy. Same 4-bh-per-XCD L2 grouping.
#define KH_IDX(row, d8) (((row) * 8 + ((d8) ^ ((row) & 7))) * 8)       // halves

__global__ __launch_bounds__(256, 4) void attn_mfma(
        const unsigned short* __restrict__ qhg, const unsigned short* __restrict__ qlg,
        const unsigned short* __restrict__ khg, const unsigned short* __restrict__ klg,
        const unsigned short* __restrict__ vhg, const unsigned short* __restrict__ vlg,
        float* __restrict__ out) {
    __shared__ __align__(16) _Float16 KhL[32 * 64];
    __shared__ __align__(16) _Float16 KlL[32 * 64];
    __shared__ __align__(16) _Float16 PhL[4][16 * 36];   // pad-36 rows: <=2-way banks
    __shared__ __align__(16) _Float16 PlL[4][16 * 36];
    __shared__ float Lp[4][16][4];

    const int lin  = blockIdx.x;
    const int bh   = (lin & 7) * 4 + ((lin >> 3) & 3);   // co-resident blocks share bh
    const int qblk = (lin >> 5) & 31;
    const int tid  = threadIdx.x;
    const int wave = tid >> 6, lane = tid & 63;
    const int l15  = lane & 15, quad = lane >> 4;
    const int qbase = qblk * 64 + wave * 16;

    // ---- Q fragments: direct f16x8 loads from separate limb planes ----
    f16x8 qh[2], qm[2];
    #pragma unroll
    for (int c = 0; c < 2; c++) {
        size_t off = (((size_t)bh * SEQ + qbase + l15) << 6) + c * 32 + quad * 8;
        qh[c] = *(const f16x8*)(qhg + off);
        qm[c] = *(const f16x8*)(qlg + off);
    }

    floatx4 och[4] = {};   // [nh] hi-scale PV acc
    floatx4 ocm[4] = {};   // [nh] 2^-11-scale PV acc
    float lsum = 0.f;

    const unsigned short* khb = khg + ((size_t)bh * SEQ << 6);
    const unsigned short* klb = klg + ((size_t)bh * SEQ << 6);
    const unsigned short* vhb = vhg + ((size_t)bh << 17);  // [64][2048] halves for this bh
    const unsigned short* vlb = vlg + ((size_t)bh << 17);

    const int kk = tid >> 3, d8 = tid & 7;

    // prologue: prefetch K tile 0 into regs
    uint4 kh_pf = *(const uint4*)(khb + ((size_t)kk << 6) + d8 * 8);
    uint4 kl_pf = *(const uint4*)(klb + ((size_t)kk << 6) + d8 * 8);

    for (int kt = 0; kt < SEQ; kt += 32) {
        BAR_LGKM();   // LDS reads from previous tile done (no vmcnt drain)

        *(uint4*)&KhL[KH_IDX(kk, d8)] = kh_pf;   // auto vmcnt wait on prefetch regs only
        *(uint4*)&KlL[KH_IDX(kk, d8)] = kl_pf;

        if (kt + 32 < SEQ) {   // prefetch K(t+1): full tile of latency tolerance
            kh_pf = *(const uint4*)(khb + ((size_t)(kt + 32 + kk) << 6) + d8 * 8);
            kl_pf = *(const uint4*)(klb + ((size_t)(kt + 32 + kk) << 6) + d8 * 8);
        }

        BAR_LGKM();   // staged K visible

        // K fragments (A-operand), direct f16x8 from LDS
        f16x8 kfh[2][2], kfl[2][2];
        #pragma unroll
        for (int ms = 0; ms < 2; ms++) {
            #pragma unroll
            for (int c = 0; c < 2; c++) {
                kfh[ms][c] = *(const f16x8*)&KhL[KH_IDX(ms * 16 + l15, c * 4 + quad)];
                kfl[ms][c] = *(const f16x8*)&KlL[KH_IDX(ms * 16 + l15, c * 4 + quad)];
            }
        }

        // QK MFMAs first (P scores in ah/am per ms handled below), then V loads issue
        // so their vmem latency hides under softmax + P LDS round-trip.
        floatx4 ah[2], am[2];
        #pragma unroll
        for (int ms = 0; ms < 2; ms++) {
            ah[ms] = (floatx4){};
            am[ms] = (floatx4){};
            #pragma unroll
            for (int c = 0; c < 2; c++) {
                ah[ms] = __builtin_amdgcn_mfma_f32_16x16x32_f16(kfh[ms][c], qh[c], ah[ms], 0, 0, 0);
                am[ms] = __builtin_amdgcn_mfma_f32_16x16x32_f16(kfh[ms][c], qm[c], am[ms], 0, 0, 0);
                am[ms] = __builtin_amdgcn_mfma_f32_16x16x32_f16(kfl[ms][c], qh[c], am[ms], 0, 0, 0);
            }
        }

        // V fragments straight from global limb planes (B-operand-shaped)
        f16x8 vfh[4], vfm[4];
        #pragma unroll
        for (int nh = 0; nh < 4; nh++) {
            size_t voff = (((size_t)(nh * 16 + l15)) << 11) + kt + quad * 8;
            vfh[nh] = *(const f16x8*)(vhb + voff);
            vfm[nh] = *(const f16x8*)(vlb + voff);
        }

        // softmax: p = exp2(s) -> P limb planes
        #pragma unroll
        for (int ms = 0; ms < 2; ms++) {
            float p[4];
            #pragma unroll
            for (int r = 0; r < 4; r++) {
                float s = ah[ms][r] + am[ms][r] * 4.8828125e-4f;
                p[r] = exp2f(s);
                lsum += p[r];
            }
            f16x4 hv, lv;
            #pragma unroll
            for (int r = 0; r < 4; r++) {
                _Float16 h = (_Float16)p[r];
                hv[r] = h;
                lv[r] = (_Float16)((p[r] - (float)h) * 2048.0f);
            }
            int poff = l15 * 36 + ms * 16 + quad * 4;
            *(f16x4*)&PhL[wave][poff] = hv;
            *(f16x4*)&PlL[wave][poff] = lv;
        }
        WAIT_LGKM();   // P writes visible to own wave's cross-lane reads (vmcnt untouched)

        // P fragments (A-operand) from limb planes; V already inbound from global
        f16x8 pfh = *(const f16x8*)&PhL[wave][l15 * 36 + quad * 8];
        f16x8 pfm = *(const f16x8*)&PlL[wave][l15 * 36 + quad * 8];
        #pragma unroll
        for (int nh = 0; nh < 4; nh++) {
            och[nh] = __builtin_amdgcn_mfma_f32_16x16x32_f16(pfh, vfh[nh], och[nh], 0, 0, 0);
            ocm[nh] = __builtin_amdgcn_mfma_f32_16x16x32_f16(pfh, vfm[nh], ocm[nh], 0, 0, 0);
            ocm[nh] = __builtin_amdgcn_mfma_f32_16x16x32_f16(pfm, vfh[nh], ocm[nh], 0, 0, 0);
        }
    }

    // ---- epilogue: merge l across quads, normalize, write ----
    Lp[wave][l15][quad] = lsum;
    WAIT_LGKM();

    int b = bh >> 4, h = bh & 15;
    float linv[4];
    #pragma unroll
    for (int r = 0; r < 4; r++) {
        float4 lv = *(const float4*)&Lp[wave][quad * 4 + r][0];
        linv[r] = 1.0f / (lv.x + lv.y + lv.z + lv.w);
    }
    #pragma unroll
    for (int nh = 0; nh < 4; nh++) {
        #pragma unroll
        for (int r = 0; r < 4; r++) {
            int token = b * SEQ + qbase + quad * 4 + r;
            float val = (och[nh][r] + ocm[nh][r] * 4.8828125e-4f) * linv[r];
            out[(size_t)token * DM + h * 64 + nh * 16 + l15] = val;
        }
    }
}

extern "C" void kernel_launch(void* const* d_in, const int* in_sizes, int n_in,
                              void* d_out, int out_size, void* d_ws, size_t ws_size,
                              hipStream_t stream) {
    const float* x       = (const float*)d_in[0];
    const float* context = (const float*)d_in[1];
    const float* Wq      = (const float*)d_in[2];
    const float* Wk      = (const float*)d_in[3];
    const float* Wv      = (const float*)d_in[4];
    const float* Wo      = (const float*)d_in[5];
    char* ws = (char*)d_ws;

    // workspace layout (~71.4 MB). Plane region at +21102592:
    //   Qh 8MB | Ql 8MB | Kh 8MB | Kl 8MB | Vh 8MB | Vl 8MB  (48 MB total)
    double* wscale   = (double*)(ws + 0);            // 4 doubles
    double* partial  = (double*)(ws + 4096);         // 256 doubles
    double* ascale_x = (double*)(ws + 8192);         // 8192 doubles (x then ctx)
    double* ascale_a = (double*)(ws + 73728);        // 4096 doubles
    signed char* wqb = (signed char*)(ws + 131072);          // 4 x 1 MB int8
    signed char* xq  = (signed char*)(ws + 4325376);         // 4 MB (cq follows)
    signed char* cq  = (signed char*)(ws + 8519680);         // 4 MB
    float* attn_out  = (float*)(ws + 4325376);               // aliases xq+cq region (16 MB)
    char* planes     = ws + 21102592;                        // 48 MB limb planes
    signed char* aq  = (signed char*)(ws + 21102592);        // aliases Q planes, used after attention

    unsigned short* qhg = (unsigned short*)planes;
    unsigned short* qlg = qhg + 4194304;
    unsigned short* khg = (unsigned short*)(planes + 16777216);
    unsigned short* klg = khg + 4194304;
    unsigned short* vhg = (unsigned short*)(planes + 33554432);
    unsigned short* vlg = vhg + 4194304;

    wsum1<<<dim3(64, 4), 256, 0, stream>>>(Wq, Wk, Wv, Wo, partial);
    wsum2<<<1, 64, 0, stream>>>(partial, wscale);
    wquant<<<dim3(1024, 4), 256, 0, stream>>>(Wq, Wk, Wv, Wo, wscale, wqb);
    aquant2<<<2 * NTOK, 256, 0, stream>>>(x, context, xq, ascale_x);

    gemm_qkv<<<dim3(24, 32), 256, 0, stream>>>(xq, cq, wqb, ascale_x, wscale, planes);

    attn_mfma<<<dim3(1024), 256, 0, stream>>>(qhg, qlg, khg, klg, vhg, vlg, attn_out);

    aquant<<<NTOK, 256, 0, stream>>>(attn_out, aq, ascale_a);
    gemm_o<<<dim3(8, 32), 256, 0, stream>>>(aq, wqb + 3145728, ascale_a, wscale + 3, (float*)d_out);
}

// Round 4
// 389.743 us; speedup vs baseline: 1.0731x; 1.0731x over previous
//
#include <hip/hip_runtime.h>
#include <math.h>

#define HEADS   16
#define DHEAD   64
#define SEQ     2048
#define NB      2
#define DM      1024
#define NTOK    4096           // NB*SEQ
#define WEPS    1e-5

using f16x8   = __attribute__((ext_vector_type(8))) _Float16;
using f16x4   = __attribute__((ext_vector_type(4))) _Float16;
using floatx4 = __attribute__((ext_vector_type(4))) float;
using i32x4   = __attribute__((ext_vector_type(4))) int;

typedef __attribute__((address_space(1))) unsigned int gu32;
typedef __attribute__((address_space(3))) unsigned int lu32;

#define WAIT_LGKM() asm volatile("s_waitcnt lgkmcnt(0)" ::: "memory")
#define BARE_BAR()  asm volatile("s_barrier" ::: "memory")

__device__ __forceinline__ unsigned short h16b(_Float16 h) {
    union { _Float16 h; unsigned short u; } c; c.h = h; return c.u;
}

// ---------------- weight |w| mean: pass 1 (partial sums in double) ----------------
__global__ void wsum1(const float* __restrict__ w0, const float* __restrict__ w1,
                      const float* __restrict__ w2, const float* __restrict__ w3,
                      double* __restrict__ partial) {
    const float* w = (blockIdx.y == 0) ? w0 : (blockIdx.y == 1) ? w1 : (blockIdx.y == 2) ? w2 : w3;
    int base = blockIdx.x * 16384;
    double s = 0.0;
    for (int i = threadIdx.x; i < 16384; i += 256)
        s += fabs((double)w[base + i]);
    __shared__ double sd[256];
    sd[threadIdx.x] = s;
    __syncthreads();
    for (int st = 128; st > 0; st >>= 1) {
        if (threadIdx.x < st) sd[threadIdx.x] += sd[threadIdx.x + st];
        __syncthreads();
    }
    if (threadIdx.x == 0) partial[blockIdx.y * 64 + blockIdx.x] = sd[0];
}

// ---------------- weight mean: pass 2 -> wscale[w] = clip(mean|w|, eps) ----------------
__global__ void wsum2(const double* __restrict__ partial, double* __restrict__ wscale) {
    int t = threadIdx.x;
    if (t < 4) {
        double s = 0.0;
        for (int i = 0; i < 64; i++) s += partial[t * 64 + i];
        double mean = s / (1024.0 * 1024.0);
        wscale[t] = (mean > WEPS) ? mean : WEPS;
    }
}

// ---------------- ternary weight quant -> int8 {-1,0,1} ----------------
__global__ void wquant(const float* __restrict__ w0, const float* __restrict__ w1,
                       const float* __restrict__ w2, const float* __restrict__ w3,
                       const double* __restrict__ wscale, signed char* __restrict__ wq) {
    int widx = blockIdx.y;
    const float* w = (widx == 0) ? w0 : (widx == 1) ? w1 : (widx == 2) ? w2 : w3;
    double ws = 1.0 / wscale[widx];
    int idx = (blockIdx.x * 256 + threadIdx.x) * 4;
    float4 wv = *(const float4*)(w + idx);
    char4 o;
    {
        double r = rint((double)wv.x * ws); r = r > 1.0 ? 1.0 : (r < -1.0 ? -1.0 : r); o.x = (signed char)r;
    } {
        double r = rint((double)wv.y * ws); r = r > 1.0 ? 1.0 : (r < -1.0 ? -1.0 : r); o.y = (signed char)r;
    } {
        double r = rint((double)wv.z * ws); r = r > 1.0 ? 1.0 : (r < -1.0 ? -1.0 : r); o.z = (signed char)r;
    } {
        double r = rint((double)wv.w * ws); r = r > 1.0 ? 1.0 : (r < -1.0 ? -1.0 : r); o.w = (signed char)r;
    }
    *(char4*)(wq + (size_t)widx * 1048576 + idx) = o;
}

// ---------------- per-token int8 absmax activation quant -> int8 ----------------
__device__ __forceinline__ void aquant_row(const float* __restrict__ row,
                                           signed char* __restrict__ dst_row,
                                           double* __restrict__ ascale_p) {
    int t = threadIdx.x;
    float4 xv = *(const float4*)(row + t * 4);
    float a = fmaxf(fmaxf(fabsf(xv.x), fabsf(xv.y)), fmaxf(fabsf(xv.z), fabsf(xv.w)));
    __shared__ float sm[256];
    sm[t] = a;
    __syncthreads();
    for (int st = 128; st > 0; st >>= 1) {
        if (t < st) sm[t] = fmaxf(sm[t], sm[t + st]);
        __syncthreads();
    }
    double mx = (double)sm[0];
    if (mx < WEPS) mx = WEPS;
    if (t == 0) *ascale_p = mx / 127.0;
    double xs = 127.0 / mx;
    char4 o;
    {
        double r = rint((double)xv.x * xs); r = r > 127.0 ? 127.0 : (r < -128.0 ? -128.0 : r); o.x = (signed char)r;
    } {
        double r = rint((double)xv.y * xs); r = r > 127.0 ? 127.0 : (r < -128.0 ? -128.0 : r); o.y = (signed char)r;
    } {
        double r = rint((double)xv.z * xs); r = r > 127.0 ? 127.0 : (r < -128.0 ? -128.0 : r); o.z = (signed char)r;
    } {
        double r = rint((double)xv.w * xs); r = r > 127.0 ? 127.0 : (r < -128.0 ? -128.0 : r); o.w = (signed char)r;
    }
    *(char4*)(dst_row + t * 4) = o;
}

__global__ void aquant(const float* __restrict__ src, signed char* __restrict__ dst,
                       double* __restrict__ ascale) {
    int tok = blockIdx.x;
    aquant_row(src + (size_t)tok * DM, dst + (size_t)tok * DM, ascale + tok);
}

// fused x + context quant: xq/cq and ascale_x/ascale_c are contiguous in ws
__global__ void aquant2(const float* __restrict__ x, const float* __restrict__ ctx,
                        signed char* __restrict__ dst, double* __restrict__ ascale) {
    int tok = blockIdx.x;
    const float* row = (tok < NTOK) ? x + (size_t)tok * DM : ctx + (size_t)(tok - NTOK) * DM;
    aquant_row(row, dst + (size_t)tok * DM, ascale + tok);
}

// ---------------- int8 MFMA GEMM core: C[m][n] = sum_k A[m][k]*W[n][k], exact i32 ----------
// m97 structure: async global_load_lds width-16 staging, 128x128 tile, BK=64.
// mode 0 (Q): separate hi/lo f16 limb planes at [b][h][t][dh] (lo at +4194304 elems)
// mode 3 (K): separate limb planes, FRAGMENT-TILED [b][h][t/32][dh/8][t%32][dh%8]
//             -> attn K-fragment f16x8 load is 4x256B segments (coalesced)
// mode 2 (V): separate limb planes, transposed+tiled [b][h][t/32][dh][t%32]
//             -> attn V-fragment f16x8 load is 1KB contiguous; ushort4 stores over t
// mode 1: plain fp32 [t][o].
__device__ __forceinline__ void gemm_core(
        const signed char* __restrict__ A, const signed char* __restrict__ W,
        const double* __restrict__ ascale, double wsc,
        void* __restrict__ outp, int mode, float prescale, int bx, int by) {
    __shared__ __align__(16) signed char lds_a[128 * 64];
    __shared__ __align__(16) signed char lds_b[128 * 64];
    const int tid  = threadIdx.x;
    const int wave = tid >> 6, lane = tid & 63;
    const int wr = wave >> 1, wc = wave & 1;
    const int quad = lane >> 4, l15 = lane & 15;
    const int row0 = by * 128, col0 = bx * 128;
    i32x4 acc[4][4] = {};

    const signed char* ga0 = A + (size_t)(row0 + (lane >> 2)) * DM + (lane & 3) * 16;
    const signed char* gb0 = W + (size_t)(col0 + (lane >> 2)) * DM + (lane & 3) * 16;

    for (int k0 = 0; k0 < DM; k0 += 64) {
        __syncthreads();
        #pragma unroll
        for (int t = 0; t < 2; t++) {
            const int i = wave + t * 4;                 // wave-uniform instr index, 8 total
            __builtin_amdgcn_global_load_lds(
                (const gu32*)(const void*)(ga0 + (size_t)i * 16 * DM + k0),
                (lu32*)(void*)(lds_a + i * 1024), 16, 0, 0);
            __builtin_amdgcn_global_load_lds(
                (const gu32*)(const void*)(gb0 + (size_t)i * 16 * DM + k0),
                (lu32*)(void*)(lds_b + i * 1024), 16, 0, 0);
        }
        __syncthreads();
        i32x4 af[4], bfr[4];
        #pragma unroll
        for (int mi = 0; mi < 4; mi++) {
            int r = wr * 64 + mi * 16 + l15;
            af[mi] = *(const i32x4*)&lds_a[r * 64 + quad * 16];
        }
        #pragma unroll
        for (int ni = 0; ni < 4; ni++) {
            int n = wc * 64 + ni * 16 + l15;
            bfr[ni] = *(const i32x4*)&lds_b[n * 64 + quad * 16];
        }
        #pragma unroll
        for (int mi = 0; mi < 4; mi++)
            #pragma unroll
            for (int ni = 0; ni < 4; ni++)
                acc[mi][ni] = __builtin_amdgcn_mfma_i32_16x16x64_i8(af[mi], bfr[ni], acc[mi][ni], 0, 0, 0);
    }

    #pragma unroll
    for (int mi = 0; mi < 4; mi++) {
        int tbase = row0 + wr * 64 + mi * 16 + quad * 4;
        if (mode == 2) {
            int bb = tbase >> 11, n = tbase & 2047;
            int tile = n >> 5, tin = n & 31;
            #pragma unroll
            for (int ni = 0; ni < 4; ni++) {
                int o = col0 + wc * 64 + ni * 16 + l15;
                int hh = o >> 6, dh = o & 63;
                ushort4 hv, lv;
                #pragma unroll
                for (int reg = 0; reg < 4; reg++) {
                    double sa = ascale[tbase + reg] * wsc;
                    float fv = (float)((double)acc[mi][ni][reg] * sa) * prescale;
                    _Float16 hl = (_Float16)fv;
                    _Float16 ml = (_Float16)((fv - (float)hl) * 2048.0f);
                    ((unsigned short*)&hv)[reg] = h16b(hl);
                    ((unsigned short*)&lv)[reg] = h16b(ml);
                }
                size_t idx = (((size_t)(bb * HEADS + hh) * 64 + tile) * 64 + dh) * 32 + tin;
                *(ushort4*)((unsigned short*)outp + idx)           = hv;
                *(ushort4*)((unsigned short*)outp + idx + 4194304) = lv;
            }
        } else {
            #pragma unroll
            for (int reg = 0; reg < 4; reg++) {
                int t = tbase + reg;
                double sa = ascale[t] * wsc;
                #pragma unroll
                for (int ni = 0; ni < 4; ni++) {
                    int o = col0 + wc * 64 + ni * 16 + l15;
                    float val = (float)((double)acc[mi][ni][reg] * sa);
                    if (mode == 1) {
                        ((float*)outp)[(size_t)t * DM + o] = val;
                    } else {
                        int bb = t >> 11, n = t & 2047, hh = o >> 6, dh = o & 63;
                        float fv = val * prescale;
                        _Float16 hl = (_Float16)fv;
                        _Float16 ml = (_Float16)((fv - (float)hl) * 2048.0f);
                        if (mode == 0) {
                            size_t idx = (((size_t)(bb * HEADS + hh) * SEQ + n) << 6) + dh;
                            ((unsigned short*)outp)[idx]           = h16b(hl);
                            ((unsigned short*)outp)[idx + 4194304] = h16b(ml);
                        } else {  // mode 3: K fragment-tiled [bh][n/32][dh/8][n%32][dh%8]
                            size_t idx = ((((size_t)(bb * HEADS + hh) * 64 + (n >> 5)) * 8 + (dh >> 3)) << 8)
                                         + ((n & 31) << 3) + (dh & 7);
                            ((unsigned short*)outp)[idx]           = h16b(hl);
                            ((unsigned short*)outp)[idx + 4194304] = h16b(ml);
                        }
                    }
                }
            }
        }
    }
}

// fused Q/K/V projections: 768 blocks = 3/CU co-resident (hides barrier drain)
// Q prescale folds softmax scale AND log2(e): 0.125 * 1.4426950408889634
__global__ __launch_bounds__(256) void gemm_qkv(
        const signed char* __restrict__ xq, const signed char* __restrict__ cq,
        const signed char* __restrict__ wqb, const double* __restrict__ ascale_x,
        const double* __restrict__ wscale, void* __restrict__ qkv) {
    const int which = blockIdx.x >> 3;          // 0=Q, 1=K, 2=V
    char* base = (char*)qkv + (size_t)which * 16777216;
    gemm_core(which == 0 ? xq : cq,
              wqb + (size_t)which * 1048576,
              ascale_x + (which ? NTOK : 0),
              wscale[which],
              base,
              which == 0 ? 0 : (which == 1 ? 3 : 2),
              which == 0 ? 0.18033688011112042f : 1.0f, blockIdx.x & 7, blockIdx.y);
}

__global__ __launch_bounds__(256) void gemm_o(
        const signed char* __restrict__ aq, const signed char* __restrict__ wo,
        const double* __restrict__ ascale, const double* __restrict__ wscale_p,
        float* __restrict__ out) {
    gemm_core(aq, wo, ascale, *wscale_p, out, 1, 1.0f, blockIdx.x, blockIdx.y);
}

// ---------------- MFMA flash attention v7: zero-LDS K/V, fragment-tiled global ------------
// v5 was LDS-pipe-bound (~87%: K+V staging + frag reads ~295K cyc/CU of 340K wall).
// v6 (V direct from [dh][t] global) died on 4KB-strided lanes: 16 segments/instr, TA-bound.
// v7: K and V limb planes are FRAGMENT-TILED by gemm_qkv (K: [bh][t/32][d/8][t%32][d%8],
// V: [bh][t/32][dh][t%32]) so every f16x8 fragment load is coalesced (V: 1KB contiguous
// per instr; K: 4x256B). No K/V LDS at all -> LDS carries only the per-wave P round-trip.
// Bare s_barrier per tile lock-steps the block's 4 waves (identical K/V addresses -> L1
// serves 3 of 4); each SIMD's 4 resident waves come from 4 unsynced blocks -> natural
// stagger hides load latency. Co-resident blocks share bh (same K/V working set, ~1.5MB
// -> L2-resident). Budget: MFMA 89K cyc/SIMD, LDS 49K/CU, TA ~35K -> wall ~55-70us.
__global__ __launch_bounds__(256, 4) void attn_mfma(
        const unsigned short* __restrict__ qhg, const unsigned short* __restrict__ qlg,
        const unsigned short* __restrict__ khg, const unsigned short* __restrict__ klg,
        const unsigned short* __restrict__ vhg, const unsigned short* __restrict__ vlg,
        float* __restrict__ out) {
    __shared__ __align__(16) _Float16 PhL[4][16 * 36];   // pad-36 rows: <=2-way banks
    __shared__ __align__(16) _Float16 PlL[4][16 * 36];
    __shared__ float Lp[4][16][4];

    const int lin  = blockIdx.x;
    const int bh   = (lin & 7) * 4 + ((lin >> 3) & 3);   // co-resident blocks share bh
    const int qblk = (lin >> 5) & 31;
    const int tid  = threadIdx.x;
    const int wave = tid >> 6, lane = tid & 63;
    const int l15  = lane & 15, quad = lane >> 4;
    const int qbase = qblk * 64 + wave * 16;

    // ---- Q fragments: direct f16x8 loads from separate limb planes ----
    f16x8 qh[2], qm[2];
    #pragma unroll
    for (int c = 0; c < 2; c++) {
        size_t off = (((size_t)bh * SEQ + qbase + l15) << 6) + c * 32 + quad * 8;
        qh[c] = *(const f16x8*)(qhg + off);
        qm[c] = *(const f16x8*)(qlg + off);
    }

    floatx4 och[4] = {};   // [nh] hi-scale PV acc
    floatx4 ocm[4] = {};   // [nh] 2^-11-scale PV acc
    float lsum = 0.f;

    const unsigned short* khb = khg + ((size_t)bh << 17);   // 131072 halves per bh
    const unsigned short* klb = klg + ((size_t)bh << 17);
    const unsigned short* vhb = vhg + ((size_t)bh << 17);
    const unsigned short* vlb = vlg + ((size_t)bh << 17);

    for (int kt = 0; kt < SEQ; kt += 32) {
        const int tile = kt >> 5;
        BARE_BAR();   // lockstep the block's waves for L1 reuse (no mem drain needed)

        // K fragments (A-operand) straight from fragment-tiled global: 4x256B/instr
        f16x8 kfh[2][2], kfl[2][2];
        #pragma unroll
        for (int ms = 0; ms < 2; ms++) {
            #pragma unroll
            for (int c = 0; c < 2; c++) {
                size_t ko = ((size_t)(tile * 8 + c * 4 + quad) << 8) + ((ms * 16 + l15) << 3);
                kfh[ms][c] = *(const f16x8*)(khb + ko);
                kfl[ms][c] = *(const f16x8*)(klb + ko);
            }
        }

        // QK MFMAs
        floatx4 ah[2], am[2];
        #pragma unroll
        for (int ms = 0; ms < 2; ms++) {
            ah[ms] = (floatx4){};
            am[ms] = (floatx4){};
            #pragma unroll
            for (int c = 0; c < 2; c++) {
                ah[ms] = __builtin_amdgcn_mfma_f32_16x16x32_f16(kfh[ms][c], qh[c], ah[ms], 0, 0, 0);
                am[ms] = __builtin_amdgcn_mfma_f32_16x16x32_f16(kfh[ms][c], qm[c], am[ms], 0, 0, 0);
                am[ms] = __builtin_amdgcn_mfma_f32_16x16x32_f16(kfl[ms][c], qh[c], am[ms], 0, 0, 0);
            }
        }

        // V fragments (B-operand) straight from fragment-tiled global: 1KB contig/instr.
        // Latency covered by softmax + P LDS round-trip + cross-block SIMD stagger.
        f16x8 vfh[4], vfm[4];
        #pragma unroll
        for (int nh = 0; nh < 4; nh++) {
            size_t vo = ((size_t)(tile * 64 + nh * 16 + l15) << 5) + quad * 8;
            vfh[nh] = *(const f16x8*)(vhb + vo);
            vfm[nh] = *(const f16x8*)(vlb + vo);
        }

        // softmax: p = exp2(s) -> P limb planes
        #pragma unroll
        for (int ms = 0; ms < 2; ms++) {
            float p[4];
            #pragma unroll
            for (int r = 0; r < 4; r++) {
                float s = ah[ms][r] + am[ms][r] * 4.8828125e-4f;
                p[r] = exp2f(s);
                lsum += p[r];
            }
            f16x4 hv, lv;
            #pragma unroll
            for (int r = 0; r < 4; r++) {
                _Float16 h = (_Float16)p[r];
                hv[r] = h;
                lv[r] = (_Float16)((p[r] - (float)h) * 2048.0f);
            }
            int poff = l15 * 36 + ms * 16 + quad * 4;
            *(f16x4*)&PhL[wave][poff] = hv;
            *(f16x4*)&PlL[wave][poff] = lv;
        }
        WAIT_LGKM();   // P writes visible to own wave's cross-lane reads (vmcnt untouched)

        // P fragments (A-operand) from limb planes; V already inbound
        f16x8 pfh = *(const f16x8*)&PhL[wave][l15 * 36 + quad * 8];
        f16x8 pfm = *(const f16x8*)&PlL[wave][l15 * 36 + quad * 8];
        #pragma unroll
        for (int nh = 0; nh < 4; nh++) {
            och[nh] = __builtin_amdgcn_mfma_f32_16x16x32_f16(pfh, vfh[nh], och[nh], 0, 0, 0);
            ocm[nh] = __builtin_amdgcn_mfma_f32_16x16x32_f16(pfh, vfm[nh], ocm[nh], 0, 0, 0);
            ocm[nh] = __builtin_amdgcn_mfma_f32_16x16x32_f16(pfm, vfh[nh], ocm[nh], 0, 0, 0);
        }
    }

    // ---- epilogue: merge l across quads, normalize, write ----
    Lp[wave][l15][quad] = lsum;
    WAIT_LGKM();

    int b = bh >> 4, h = bh & 15;
    float linv[4];
    #pragma unroll
    for (int r = 0; r < 4; r++) {
        float4 lv = *(const float4*)&Lp[wave][quad * 4 + r][0];
        linv[r] = 1.0f / (lv.x + lv.y + lv.z + lv.w);
    }
    #pragma unroll
    for (int nh = 0; nh < 4; nh++) {
        #pragma unroll
        for (int r = 0; r < 4; r++) {
            int token = b * SEQ + qbase + quad * 4 + r;
            float val = (och[nh][r] + ocm[nh][r] * 4.8828125e-4f) * linv[r];
            out[(size_t)token * DM + h * 64 + nh * 16 + l15] = val;
        }
    }
}

extern "C" void kernel_launch(void* const* d_in, const int* in_sizes, int n_in,
                              void* d_out, int out_size, void* d_ws, size_t ws_size,
                              hipStream_t stream) {
    const float* x       = (const float*)d_in[0];
    const float* context = (const float*)d_in[1];
    const float* Wq      = (const float*)d_in[2];
    const float* Wk      = (const float*)d_in[3];
    const float* Wv      = (const float*)d_in[4];
    const float* Wo      = (const float*)d_in[5];
    char* ws = (char*)d_ws;

    // workspace layout (~71.4 MB). Plane region at +21102592:
    //   Qh 8MB | Ql 8MB | Kh 8MB | Kl 8MB | Vh 8MB | Vl 8MB  (48 MB total)
    double* wscale   = (double*)(ws + 0);            // 4 doubles
    double* partial  = (double*)(ws + 4096);         // 256 doubles
    double* ascale_x = (double*)(ws + 8192);         // 8192 doubles (x then ctx)
    double* ascale_a = (double*)(ws + 73728);        // 4096 doubles
    signed char* wqb = (signed char*)(ws + 131072);          // 4 x 1 MB int8
    signed char* xq  = (signed char*)(ws + 4325376);         // 4 MB (cq follows)
    signed char* cq  = (signed char*)(ws + 8519680);         // 4 MB
    float* attn_out  = (float*)(ws + 4325376);               // aliases xq+cq region (16 MB)
    char* planes     = ws + 21102592;                        // 48 MB limb planes
    signed char* aq  = (signed char*)(ws + 21102592);        // aliases Q planes, used after attention

    unsigned short* qhg = (unsigned short*)planes;
    unsigned short* qlg = qhg + 4194304;
    unsigned short* khg = (unsigned short*)(planes + 16777216);
    unsigned short* klg = khg + 4194304;
    unsigned short* vhg = (unsigned short*)(planes + 33554432);
    unsigned short* vlg = vhg + 4194304;

    wsum1<<<dim3(64, 4), 256, 0, stream>>>(Wq, Wk, Wv, Wo, partial);
    wsum2<<<1, 64, 0, stream>>>(partial, wscale);
    wquant<<<dim3(1024, 4), 256, 0, stream>>>(Wq, Wk, Wv, Wo, wscale, wqb);
    aquant2<<<2 * NTOK, 256, 0, stream>>>(x, context, xq, ascale_x);

    gemm_qkv<<<dim3(24, 32), 256, 0, stream>>>(xq, cq, wqb, ascale_x, wscale, planes);

    attn_mfma<<<dim3(1024), 256, 0, stream>>>(qhg, qlg, khg, klg, vhg, vlg, attn_out);

    aquant<<<NTOK, 256, 0, stream>>>(attn_out, aq, ascale_a);
    gemm_o<<<dim3(8, 32), 256, 0, stream>>>(aq, wqb + 3145728, ascale_a, wscale + 3, (float*)d_out);
}

// Round 5
// 362.424 us; speedup vs baseline: 1.1540x; 1.0754x over previous
//
#include <hip/hip_runtime.h>
#include <math.h>

#define HEADS   16
#define DHEAD   64
#define SEQ     2048
#define NB      2
#define DM      1024
#define NTOK    4096           // NB*SEQ
#define WEPS    1e-5

using f16x8   = __attribute__((ext_vector_type(8))) _Float16;
using f16x4   = __attribute__((ext_vector_type(4))) _Float16;
using floatx4 = __attribute__((ext_vector_type(4))) float;
using i32x4   = __attribute__((ext_vector_type(4))) int;

typedef __attribute__((address_space(1))) unsigned int gu32;
typedef __attribute__((address_space(3))) unsigned int lu32;

// lgkmcnt(0)-only barrier: does NOT drain vmcnt (register/global prefetch survives).
#define BAR_LGKM()  asm volatile("s_waitcnt lgkmcnt(0)\n\ts_barrier" ::: "memory")
#define WAIT_LGKM() asm volatile("s_waitcnt lgkmcnt(0)" ::: "memory")

__device__ __forceinline__ unsigned short h16b(_Float16 h) {
    union { _Float16 h; unsigned short u; } c; c.h = h; return c.u;
}

// ---------------- weight |w| mean: pass 1 (partial sums in double) ----------------
__global__ void wsum1(const float* __restrict__ w0, const float* __restrict__ w1,
                      const float* __restrict__ w2, const float* __restrict__ w3,
                      double* __restrict__ partial) {
    const float* w = (blockIdx.y == 0) ? w0 : (blockIdx.y == 1) ? w1 : (blockIdx.y == 2) ? w2 : w3;
    int base = blockIdx.x * 16384;
    double s = 0.0;
    for (int i = threadIdx.x; i < 16384; i += 256)
        s += fabs((double)w[base + i]);
    __shared__ double sd[256];
    sd[threadIdx.x] = s;
    __syncthreads();
    for (int st = 128; st > 0; st >>= 1) {
        if (threadIdx.x < st) sd[threadIdx.x] += sd[threadIdx.x + st];
        __syncthreads();
    }
    if (threadIdx.x == 0) partial[blockIdx.y * 64 + blockIdx.x] = sd[0];
}

// ---------------- weight mean: pass 2 -> wscale[w] = clip(mean|w|, eps) ----------------
__global__ void wsum2(const double* __restrict__ partial, double* __restrict__ wscale) {
    int t = threadIdx.x;
    if (t < 4) {
        double s = 0.0;
        for (int i = 0; i < 64; i++) s += partial[t * 64 + i];
        double mean = s / (1024.0 * 1024.0);
        wscale[t] = (mean > WEPS) ? mean : WEPS;
    }
}

// ---------------- ternary weight quant -> int8 {-1,0,1} ----------------
__global__ void wquant(const float* __restrict__ w0, const float* __restrict__ w1,
                       const float* __restrict__ w2, const float* __restrict__ w3,
                       const double* __restrict__ wscale, signed char* __restrict__ wq) {
    int widx = blockIdx.y;
    const float* w = (widx == 0) ? w0 : (widx == 1) ? w1 : (widx == 2) ? w2 : w3;
    double ws = 1.0 / wscale[widx];
    int idx = (blockIdx.x * 256 + threadIdx.x) * 4;
    float4 wv = *(const float4*)(w + idx);
    char4 o;
    {
        double r = rint((double)wv.x * ws); r = r > 1.0 ? 1.0 : (r < -1.0 ? -1.0 : r); o.x = (signed char)r;
    } {
        double r = rint((double)wv.y * ws); r = r > 1.0 ? 1.0 : (r < -1.0 ? -1.0 : r); o.y = (signed char)r;
    } {
        double r = rint((double)wv.z * ws); r = r > 1.0 ? 1.0 : (r < -1.0 ? -1.0 : r); o.z = (signed char)r;
    } {
        double r = rint((double)wv.w * ws); r = r > 1.0 ? 1.0 : (r < -1.0 ? -1.0 : r); o.w = (signed char)r;
    }
    *(char4*)(wq + (size_t)widx * 1048576 + idx) = o;
}

// ---------------- per-token int8 absmax activation quant -> int8 ----------------
__device__ __forceinline__ void aquant_row(const float* __restrict__ row,
                                           signed char* __restrict__ dst_row,
                                           double* __restrict__ ascale_p) {
    int t = threadIdx.x;
    float4 xv = *(const float4*)(row + t * 4);
    float a = fmaxf(fmaxf(fabsf(xv.x), fabsf(xv.y)), fmaxf(fabsf(xv.z), fabsf(xv.w)));
    __shared__ float sm[256];
    sm[t] = a;
    __syncthreads();
    for (int st = 128; st > 0; st >>= 1) {
        if (t < st) sm[t] = fmaxf(sm[t], sm[t + st]);
        __syncthreads();
    }
    double mx = (double)sm[0];
    if (mx < WEPS) mx = WEPS;
    if (t == 0) *ascale_p = mx / 127.0;
    double xs = 127.0 / mx;
    char4 o;
    {
        double r = rint((double)xv.x * xs); r = r > 127.0 ? 127.0 : (r < -128.0 ? -128.0 : r); o.x = (signed char)r;
    } {
        double r = rint((double)xv.y * xs); r = r > 127.0 ? 127.0 : (r < -128.0 ? -128.0 : r); o.y = (signed char)r;
    } {
        double r = rint((double)xv.z * xs); r = r > 127.0 ? 127.0 : (r < -128.0 ? -128.0 : r); o.z = (signed char)r;
    } {
        double r = rint((double)xv.w * xs); r = r > 127.0 ? 127.0 : (r < -128.0 ? -128.0 : r); o.w = (signed char)r;
    }
    *(char4*)(dst_row + t * 4) = o;
}

__global__ void aquant(const float* __restrict__ src, signed char* __restrict__ dst,
                       double* __restrict__ ascale) {
    int tok = blockIdx.x;
    aquant_row(src + (size_t)tok * DM, dst + (size_t)tok * DM, ascale + tok);
}

// fused x + context quant: xq/cq and ascale_x/ascale_c are contiguous in ws
__global__ void aquant2(const float* __restrict__ x, const float* __restrict__ ctx,
                        signed char* __restrict__ dst, double* __restrict__ ascale) {
    int tok = blockIdx.x;
    const float* row = (tok < NTOK) ? x + (size_t)tok * DM : ctx + (size_t)(tok - NTOK) * DM;
    aquant_row(row, dst + (size_t)tok * DM, ascale + tok);
}

// ---------------- int8 MFMA GEMM core: C[m][n] = sum_k A[m][k]*W[n][k], exact i32 ----------
// m97 structure: async global_load_lds width-16 staging, 128x128 tile, BK=64.
// mode 0 (Q,K): separate hi/lo f16 limb planes at [b][h][t][dh] (lo at +4194304 elems)
// mode 2 (V):   separate limb planes, transposed+FRAGMENT-TILED [b][h][t/32][dh][t%32]
//               -> attn V-fragment f16x8 load is 1KB contiguous; ushort4 stores over t
// mode 1: plain fp32 [t][o].
__device__ __forceinline__ void gemm_core(
        const signed char* __restrict__ A, const signed char* __restrict__ W,
        const double* __restrict__ ascale, double wsc,
        void* __restrict__ outp, int mode, float prescale, int bx, int by) {
    __shared__ __align__(16) signed char lds_a[128 * 64];
    __shared__ __align__(16) signed char lds_b[128 * 64];
    const int tid  = threadIdx.x;
    const int wave = tid >> 6, lane = tid & 63;
    const int wr = wave >> 1, wc = wave & 1;
    const int quad = lane >> 4, l15 = lane & 15;
    const int row0 = by * 128, col0 = bx * 128;
    i32x4 acc[4][4] = {};

    const signed char* ga0 = A + (size_t)(row0 + (lane >> 2)) * DM + (lane & 3) * 16;
    const signed char* gb0 = W + (size_t)(col0 + (lane >> 2)) * DM + (lane & 3) * 16;

    for (int k0 = 0; k0 < DM; k0 += 64) {
        __syncthreads();
        #pragma unroll
        for (int t = 0; t < 2; t++) {
            const int i = wave + t * 4;                 // wave-uniform instr index, 8 total
            __builtin_amdgcn_global_load_lds(
                (const gu32*)(const void*)(ga0 + (size_t)i * 16 * DM + k0),
                (lu32*)(void*)(lds_a + i * 1024), 16, 0, 0);
            __builtin_amdgcn_global_load_lds(
                (const gu32*)(const void*)(gb0 + (size_t)i * 16 * DM + k0),
                (lu32*)(void*)(lds_b + i * 1024), 16, 0, 0);
        }
        __syncthreads();
        i32x4 af[4], bfr[4];
        #pragma unroll
        for (int mi = 0; mi < 4; mi++) {
            int r = wr * 64 + mi * 16 + l15;
            af[mi] = *(const i32x4*)&lds_a[r * 64 + quad * 16];
        }
        #pragma unroll
        for (int ni = 0; ni < 4; ni++) {
            int n = wc * 64 + ni * 16 + l15;
            bfr[ni] = *(const i32x4*)&lds_b[n * 64 + quad * 16];
        }
        #pragma unroll
        for (int mi = 0; mi < 4; mi++)
            #pragma unroll
            for (int ni = 0; ni < 4; ni++)
                acc[mi][ni] = __builtin_amdgcn_mfma_i32_16x16x64_i8(af[mi], bfr[ni], acc[mi][ni], 0, 0, 0);
    }

    #pragma unroll
    for (int mi = 0; mi < 4; mi++) {
        int tbase = row0 + wr * 64 + mi * 16 + quad * 4;
        if (mode == 2) {
            int bb = tbase >> 11, n = tbase & 2047;
            int tile = n >> 5, tin = n & 31;
            #pragma unroll
            for (int ni = 0; ni < 4; ni++) {
                int o = col0 + wc * 64 + ni * 16 + l15;
                int hh = o >> 6, dh = o & 63;
                ushort4 hv, lv;
                #pragma unroll
                for (int reg = 0; reg < 4; reg++) {
                    double sa = ascale[tbase + reg] * wsc;
                    float fv = (float)((double)acc[mi][ni][reg] * sa) * prescale;
                    _Float16 hl = (_Float16)fv;
                    _Float16 ml = (_Float16)((fv - (float)hl) * 2048.0f);
                    ((unsigned short*)&hv)[reg] = h16b(hl);
                    ((unsigned short*)&lv)[reg] = h16b(ml);
                }
                size_t idx = (((size_t)(bb * HEADS + hh) * 64 + tile) * 64 + dh) * 32 + tin;
                *(ushort4*)((unsigned short*)outp + idx)           = hv;
                *(ushort4*)((unsigned short*)outp + idx + 4194304) = lv;
            }
        } else {
            #pragma unroll
            for (int reg = 0; reg < 4; reg++) {
                int t = tbase + reg;
                double sa = ascale[t] * wsc;
                #pragma unroll
                for (int ni = 0; ni < 4; ni++) {
                    int o = col0 + wc * 64 + ni * 16 + l15;
                    float val = (float)((double)acc[mi][ni][reg] * sa);
                    if (mode == 1) {
                        ((float*)outp)[(size_t)t * DM + o] = val;
                    } else {
                        int bb = t >> 11, n = t & 2047, hh = o >> 6, dh = o & 63;
                        float fv = val * prescale;
                        _Float16 hl = (_Float16)fv;
                        _Float16 ml = (_Float16)((fv - (float)hl) * 2048.0f);
                        size_t idx = (((size_t)(bb * HEADS + hh) * SEQ + n) << 6) + dh;
                        ((unsigned short*)outp)[idx]           = h16b(hl);
                        ((unsigned short*)outp)[idx + 4194304] = h16b(ml);
                    }
                }
            }
        }
    }
}

// fused Q/K/V projections: 768 blocks = 3/CU co-resident (hides barrier drain)
// Q prescale folds softmax scale AND log2(e): 0.125 * 1.4426950408889634
__global__ __launch_bounds__(256) void gemm_qkv(
        const signed char* __restrict__ xq, const signed char* __restrict__ cq,
        const signed char* __restrict__ wqb, const double* __restrict__ ascale_x,
        const double* __restrict__ wscale, void* __restrict__ qkv) {
    const int which = blockIdx.x >> 3;          // 0=Q, 1=K, 2=V
    char* base = (char*)qkv + (size_t)which * 16777216;
    gemm_core(which == 0 ? xq : cq,
              wqb + (size_t)which * 1048576,
              ascale_x + (which ? NTOK : 0),
              wscale[which],
              base,
              which == 2 ? 2 : 0,
              which == 0 ? 0.18033688011112042f : 1.0f, blockIdx.x & 7, blockIdx.y);
}

__global__ __launch_bounds__(256) void gemm_o(
        const signed char* __restrict__ aq, const signed char* __restrict__ wo,
        const double* __restrict__ ascale, const double* __restrict__ wscale_p,
        float* __restrict__ out) {
    gemm_core(aq, wo, ascale, *wscale_p, out, 1, 1.0f, blockIdx.x, blockIdx.y);
}

// ---------------- MFMA flash attention v8: K via LDS (prefetched), V via L1 ---------------
// Pipe-split synthesis of v5 (all-LDS, LDS 87% = 141us) and v7 (all-global, latency +
// L1-bound = 237us): K + P ride the proven v5 LDS path (K(t+1) register-prefetched across
// lgkm-only barriers -> K never on the critical path); V rides the vector-mem/L1 path from
// the fragment-tiled global planes ([bh][t/32][dh][t%32], 1KB contiguous per f16x8 instr),
// issued at the TOP of the iteration so QK MFMAs + softmax (~350 cyc) cover L1/L2 latency.
// Per-wave-tile: LDS ~170 cyc (was 290), L1 8KB ~130 cyc, MFMA ~116 -> no pipe >60%.
// Co-resident blocks share bh (L1 serves the 16x intra-CU K/V re-read).
#define KH_IDX(row, d8) (((row) * 8 + ((d8) ^ ((row) & 7))) * 8)       // halves

__global__ __launch_bounds__(256, 4) void attn_mfma(
        const unsigned short* __restrict__ qhg, const unsigned short* __restrict__ qlg,
        const unsigned short* __restrict__ khg, const unsigned short* __restrict__ klg,
        const unsigned short* __restrict__ vhg, const unsigned short* __restrict__ vlg,
        float* __restrict__ out) {
    __shared__ __align__(16) _Float16 KhL[32 * 64];
    __shared__ __align__(16) _Float16 KlL[32 * 64];
    __shared__ __align__(16) _Float16 PhL[4][16 * 36];   // pad-36 rows: <=2-way banks
    __shared__ __align__(16) _Float16 PlL[4][16 * 36];
    __shared__ float Lp[4][16][4];

    const int lin  = blockIdx.x;
    const int bh   = (lin & 7) * 4 + ((lin >> 3) & 3);   // co-resident blocks share bh
    const int qblk = (lin >> 5) & 31;
    const int tid  = threadIdx.x;
    const int wave = tid >> 6, lane = tid & 63;
    const int l15  = lane & 15, quad = lane >> 4;
    const int qbase = qblk * 64 + wave * 16;

    // ---- Q fragments: direct f16x8 loads from separate limb planes ----
    f16x8 qh[2], qm[2];
    #pragma unroll
    for (int c = 0; c < 2; c++) {
        size_t off = (((size_t)bh * SEQ + qbase + l15) << 6) + c * 32 + quad * 8;
        qh[c] = *(const f16x8*)(qhg + off);
        qm[c] = *(const f16x8*)(qlg + off);
    }

    floatx4 och[4] = {};   // [nh] hi-scale PV acc
    floatx4 ocm[4] = {};   // [nh] 2^-11-scale PV acc
    float lsum = 0.f;

    const unsigned short* khb = khg + ((size_t)bh * SEQ << 6);   // [t][dh] plane
    const unsigned short* klb = klg + ((size_t)bh * SEQ << 6);
    const unsigned short* vhb = vhg + ((size_t)bh << 17);        // fragment-tiled plane
    const unsigned short* vlb = vlg + ((size_t)bh << 17);

    const int kk = tid >> 3, d8 = tid & 7;

    // prologue: prefetch K tile 0 into regs
    uint4 kh_pf = *(const uint4*)(khb + ((size_t)kk << 6) + d8 * 8);
    uint4 kl_pf = *(const uint4*)(klb + ((size_t)kk << 6) + d8 * 8);

    for (int kt = 0; kt < SEQ; kt += 32) {
        const int tile = kt >> 5;
        BAR_LGKM();   // LDS reads from previous tile done (no vmcnt drain)

        *(uint4*)&KhL[KH_IDX(kk, d8)] = kh_pf;   // auto vmcnt wait on K prefetch regs only
        *(uint4*)&KlL[KH_IDX(kk, d8)] = kl_pf;

        // V fragments for THIS tile from fragment-tiled global (1KB contiguous/instr).
        // Consumed at PV: slack = K-stage + QK MFMAs + softmax + P round-trip.
        f16x8 vfh[4], vfm[4];
        #pragma unroll
        for (int nh = 0; nh < 4; nh++) {
            size_t vo = ((size_t)(tile * 64 + nh * 16 + l15) << 5) + quad * 8;
            vfh[nh] = *(const f16x8*)(vhb + vo);
            vfm[nh] = *(const f16x8*)(vlb + vo);
        }

        if (kt + 32 < SEQ) {   // prefetch K(t+1): full tile of latency tolerance
            kh_pf = *(const uint4*)(khb + ((size_t)(kt + 32 + kk) << 6) + d8 * 8);
            kl_pf = *(const uint4*)(klb + ((size_t)(kt + 32 + kk) << 6) + d8 * 8);
        }

        BAR_LGKM();   // staged K visible

        // K fragments (A-operand), direct f16x8 from LDS
        f16x8 kfh[2][2], kfl[2][2];
        #pragma unroll
        for (int ms = 0; ms < 2; ms++) {
            #pragma unroll
            for (int c = 0; c < 2; c++) {
                kfh[ms][c] = *(const f16x8*)&KhL[KH_IDX(ms * 16 + l15, c * 4 + quad)];
                kfl[ms][c] = *(const f16x8*)&KlL[KH_IDX(ms * 16 + l15, c * 4 + quad)];
            }
        }

        // QK MFMAs
        floatx4 ah[2], am[2];
        #pragma unroll
        for (int ms = 0; ms < 2; ms++) {
            ah[ms] = (floatx4){};
            am[ms] = (floatx4){};
            #pragma unroll
            for (int c = 0; c < 2; c++) {
                ah[ms] = __builtin_amdgcn_mfma_f32_16x16x32_f16(kfh[ms][c], qh[c], ah[ms], 0, 0, 0);
                am[ms] = __builtin_amdgcn_mfma_f32_16x16x32_f16(kfh[ms][c], qm[c], am[ms], 0, 0, 0);
                am[ms] = __builtin_amdgcn_mfma_f32_16x16x32_f16(kfl[ms][c], qh[c], am[ms], 0, 0, 0);
            }
        }

        // softmax: p = exp2(s) -> P limb planes
        #pragma unroll
        for (int ms = 0; ms < 2; ms++) {
            float p[4];
            #pragma unroll
            for (int r = 0; r < 4; r++) {
                float s = ah[ms][r] + am[ms][r] * 4.8828125e-4f;
                p[r] = exp2f(s);
                lsum += p[r];
            }
            f16x4 hv, lv;
            #pragma unroll
            for (int r = 0; r < 4; r++) {
                _Float16 h = (_Float16)p[r];
                hv[r] = h;
                lv[r] = (_Float16)((p[r] - (float)h) * 2048.0f);
            }
            int poff = l15 * 36 + ms * 16 + quad * 4;
            *(f16x4*)&PhL[wave][poff] = hv;
            *(f16x4*)&PlL[wave][poff] = lv;
        }
        WAIT_LGKM();   // P writes visible to own wave's cross-lane reads (vmcnt untouched)

        // P fragments (A-operand) from limb planes; V already inbound from L1
        f16x8 pfh = *(const f16x8*)&PhL[wave][l15 * 36 + quad * 8];
        f16x8 pfm = *(const f16x8*)&PlL[wave][l15 * 36 + quad * 8];
        #pragma unroll
        for (int nh = 0; nh < 4; nh++) {
            och[nh] = __builtin_amdgcn_mfma_f32_16x16x32_f16(pfh, vfh[nh], och[nh], 0, 0, 0);
            ocm[nh] = __builtin_amdgcn_mfma_f32_16x16x32_f16(pfh, vfm[nh], ocm[nh], 0, 0, 0);
            ocm[nh] = __builtin_amdgcn_mfma_f32_16x16x32_f16(pfm, vfh[nh], ocm[nh], 0, 0, 0);
        }
    }

    // ---- epilogue: merge l across quads, normalize, write ----
    Lp[wave][l15][quad] = lsum;
    WAIT_LGKM();

    int b = bh >> 4, h = bh & 15;
    float linv[4];
    #pragma unroll
    for (int r = 0; r < 4; r++) {
        float4 lv = *(const float4*)&Lp[wave][quad * 4 + r][0];
        linv[r] = 1.0f / (lv.x + lv.y + lv.z + lv.w);
    }
    #pragma unroll
    for (int nh = 0; nh < 4; nh++) {
        #pragma unroll
        for (int r = 0; r < 4; r++) {
            int token = b * SEQ + qbase + quad * 4 + r;
            float val = (och[nh][r] + ocm[nh][r] * 4.8828125e-4f) * linv[r];
            out[(size_t)token * DM + h * 64 + nh * 16 + l15] = val;
        }
    }
}

extern "C" void kernel_launch(void* const* d_in, const int* in_sizes, int n_in,
                              void* d_out, int out_size, void* d_ws, size_t ws_size,
                              hipStream_t stream) {
    const float* x       = (const float*)d_in[0];
    const float* context = (const float*)d_in[1];
    const float* Wq      = (const float*)d_in[2];
    const float* Wk      = (const float*)d_in[3];
    const float* Wv      = (const float*)d_in[4];
    const float* Wo      = (const float*)d_in[5];
    char* ws = (char*)d_ws;

    // workspace layout (~71.4 MB). Plane region at +21102592:
    //   Qh 8MB | Ql 8MB | Kh 8MB | Kl 8MB | Vh 8MB | Vl 8MB  (48 MB total)
    double* wscale   = (double*)(ws + 0);            // 4 doubles
    double* partial  = (double*)(ws + 4096);         // 256 doubles
    double* ascale_x = (double*)(ws + 8192);         // 8192 doubles (x then ctx)
    double* ascale_a = (double*)(ws + 73728);        // 4096 doubles
    signed char* wqb = (signed char*)(ws + 131072);          // 4 x 1 MB int8
    signed char* xq  = (signed char*)(ws + 4325376);         // 4 MB (cq follows)
    signed char* cq  = (signed char*)(ws + 8519680);         // 4 MB
    float* attn_out  = (float*)(ws + 4325376);               // aliases xq+cq region (16 MB)
    char* planes     = ws + 21102592;                        // 48 MB limb planes
    signed char* aq  = (signed char*)(ws + 21102592);        // aliases Q planes, used after attention

    unsigned short* qhg = (unsigned short*)planes;
    unsigned short* qlg = qhg + 4194304;
    unsigned short* khg = (unsigned short*)(planes + 16777216);
    unsigned short* klg = khg + 4194304;
    unsigned short* vhg = (unsigned short*)(planes + 33554432);
    unsigned short* vlg = vhg + 4194304;

    wsum1<<<dim3(64, 4), 256, 0, stream>>>(Wq, Wk, Wv, Wo, partial);
    wsum2<<<1, 64, 0, stream>>>(partial, wscale);
    wquant<<<dim3(1024, 4), 256, 0, stream>>>(Wq, Wk, Wv, Wo, wscale, wqb);
    aquant2<<<2 * NTOK, 256, 0, stream>>>(x, context, xq, ascale_x);

    gemm_qkv<<<dim3(24, 32), 256, 0, stream>>>(xq, cq, wqb, ascale_x, wscale, planes);

    attn_mfma<<<dim3(1024), 256, 0, stream>>>(qhg, qlg, khg, klg, vhg, vlg, attn_out);

    aquant<<<NTOK, 256, 0, stream>>>(attn_out, aq, ascale_a);
    gemm_o<<<dim3(8, 32), 256, 0, stream>>>(aq, wqb + 3145728, ascale_a, wscale + 3, (float*)d_out);
}

// Round 6
// 314.300 us; speedup vs baseline: 1.3307x; 1.1531x over previous
//
#include <hip/hip_runtime.h>
#include <math.h>

#define HEADS   16
#define DHEAD   64
#define SEQ     2048
#define NB      2
#define DM      1024
#define NTOK    4096           // NB*SEQ
#define WEPS    1e-5

using f16x8   = __attribute__((ext_vector_type(8))) _Float16;
using f16x4   = __attribute__((ext_vector_type(4))) _Float16;
using floatx4 = __attribute__((ext_vector_type(4))) float;
using i32x4   = __attribute__((ext_vector_type(4))) int;

typedef __attribute__((address_space(1))) unsigned int gu32;
typedef __attribute__((address_space(3))) unsigned int lu32;

// lgkmcnt(0)-only barrier: does NOT drain vmcnt (register/global prefetch survives).
#define BAR_LGKM()  asm volatile("s_waitcnt lgkmcnt(0)\n\ts_barrier" ::: "memory")
#define WAIT_LGKM() asm volatile("s_waitcnt lgkmcnt(0)" ::: "memory")

__device__ __forceinline__ unsigned short h16b(_Float16 h) {
    union { _Float16 h; unsigned short u; } c; c.h = h; return c.u;
}

// ---------------- weight |w| mean: pass 1 (partial sums in double) ----------------
__global__ void wsum1(const float* __restrict__ w0, const float* __restrict__ w1,
                      const float* __restrict__ w2, const float* __restrict__ w3,
                      double* __restrict__ partial) {
    const float* w = (blockIdx.y == 0) ? w0 : (blockIdx.y == 1) ? w1 : (blockIdx.y == 2) ? w2 : w3;
    int base = blockIdx.x * 16384;
    double s = 0.0;
    for (int i = threadIdx.x; i < 16384; i += 256)
        s += fabs((double)w[base + i]);
    __shared__ double sd[256];
    sd[threadIdx.x] = s;
    __syncthreads();
    for (int st = 128; st > 0; st >>= 1) {
        if (threadIdx.x < st) sd[threadIdx.x] += sd[threadIdx.x + st];
        __syncthreads();
    }
    if (threadIdx.x == 0) partial[blockIdx.y * 64 + blockIdx.x] = sd[0];
}

// ---------------- weight mean: pass 2 -> wscale[w] = clip(mean|w|, eps) ----------------
__global__ void wsum2(const double* __restrict__ partial, double* __restrict__ wscale) {
    int t = threadIdx.x;
    if (t < 4) {
        double s = 0.0;
        for (int i = 0; i < 64; i++) s += partial[t * 64 + i];
        double mean = s / (1024.0 * 1024.0);
        wscale[t] = (mean > WEPS) ? mean : WEPS;
    }
}

// ---------------- ternary weight quant -> int8 {-1,0,1} ----------------
__global__ void wquant(const float* __restrict__ w0, const float* __restrict__ w1,
                       const float* __restrict__ w2, const float* __restrict__ w3,
                       const double* __restrict__ wscale, signed char* __restrict__ wq) {
    int widx = blockIdx.y;
    const float* w = (widx == 0) ? w0 : (widx == 1) ? w1 : (widx == 2) ? w2 : w3;
    double ws = 1.0 / wscale[widx];
    int idx = (blockIdx.x * 256 + threadIdx.x) * 4;
    float4 wv = *(const float4*)(w + idx);
    char4 o;
    {
        double r = rint((double)wv.x * ws); r = r > 1.0 ? 1.0 : (r < -1.0 ? -1.0 : r); o.x = (signed char)r;
    } {
        double r = rint((double)wv.y * ws); r = r > 1.0 ? 1.0 : (r < -1.0 ? -1.0 : r); o.y = (signed char)r;
    } {
        double r = rint((double)wv.z * ws); r = r > 1.0 ? 1.0 : (r < -1.0 ? -1.0 : r); o.z = (signed char)r;
    } {
        double r = rint((double)wv.w * ws); r = r > 1.0 ? 1.0 : (r < -1.0 ? -1.0 : r); o.w = (signed char)r;
    }
    *(char4*)(wq + (size_t)widx * 1048576 + idx) = o;
}

// ---------------- per-token int8 absmax activation quant -> int8 ----------------
__device__ __forceinline__ void aquant_row(const float* __restrict__ row,
                                           signed char* __restrict__ dst_row,
                                           double* __restrict__ ascale_p) {
    int t = threadIdx.x;
    float4 xv = *(const float4*)(row + t * 4);
    float a = fmaxf(fmaxf(fabsf(xv.x), fabsf(xv.y)), fmaxf(fabsf(xv.z), fabsf(xv.w)));
    __shared__ float sm[256];
    sm[t] = a;
    __syncthreads();
    for (int st = 128; st > 0; st >>= 1) {
        if (t < st) sm[t] = fmaxf(sm[t], sm[t + st]);
        __syncthreads();
    }
    double mx = (double)sm[0];
    if (mx < WEPS) mx = WEPS;
    if (t == 0) *ascale_p = mx / 127.0;
    double xs = 127.0 / mx;
    char4 o;
    {
        double r = rint((double)xv.x * xs); r = r > 127.0 ? 127.0 : (r < -128.0 ? -128.0 : r); o.x = (signed char)r;
    } {
        double r = rint((double)xv.y * xs); r = r > 127.0 ? 127.0 : (r < -128.0 ? -128.0 : r); o.y = (signed char)r;
    } {
        double r = rint((double)xv.z * xs); r = r > 127.0 ? 127.0 : (r < -128.0 ? -128.0 : r); o.z = (signed char)r;
    } {
        double r = rint((double)xv.w * xs); r = r > 127.0 ? 127.0 : (r < -128.0 ? -128.0 : r); o.w = (signed char)r;
    }
    *(char4*)(dst_row + t * 4) = o;
}

__global__ void aquant(const float* __restrict__ src, signed char* __restrict__ dst,
                       double* __restrict__ ascale) {
    int tok = blockIdx.x;
    aquant_row(src + (size_t)tok * DM, dst + (size_t)tok * DM, ascale + tok);
}

// fused x + context quant: xq/cq and ascale_x/ascale_c are contiguous in ws
__global__ void aquant2(const float* __restrict__ x, const float* __restrict__ ctx,
                        signed char* __restrict__ dst, double* __restrict__ ascale) {
    int tok = blockIdx.x;
    const float* row = (tok < NTOK) ? x + (size_t)tok * DM : ctx + (size_t)(tok - NTOK) * DM;
    aquant_row(row, dst + (size_t)tok * DM, ascale + tok);
}

// ---------------- int8 MFMA GEMM core: C[m][n] = sum_k A[m][k]*W[n][k], exact i32 ----------
// m97 structure: async global_load_lds width-16 staging, 128x128 tile, BK=64.
// mode 0 (Q,K): separate hi/lo f16 limb planes at [b][h][t][dh] (lo at +4194304 elems)
// mode 2 (V):   separate limb planes, transposed+FRAGMENT-TILED [b][h][t/32][dh][t%32]
//               -> attn V-fragment f16x8 load is 1KB contiguous; ushort4 stores over t
// mode 1: plain fp32 [t][o].
__device__ __forceinline__ void gemm_core(
        const signed char* __restrict__ A, const signed char* __restrict__ W,
        const double* __restrict__ ascale, double wsc,
        void* __restrict__ outp, int mode, float prescale, int bx, int by) {
    __shared__ __align__(16) signed char lds_a[128 * 64];
    __shared__ __align__(16) signed char lds_b[128 * 64];
    const int tid  = threadIdx.x;
    const int wave = tid >> 6, lane = tid & 63;
    const int wr = wave >> 1, wc = wave & 1;
    const int quad = lane >> 4, l15 = lane & 15;
    const int row0 = by * 128, col0 = bx * 128;
    i32x4 acc[4][4] = {};

    const signed char* ga0 = A + (size_t)(row0 + (lane >> 2)) * DM + (lane & 3) * 16;
    const signed char* gb0 = W + (size_t)(col0 + (lane >> 2)) * DM + (lane & 3) * 16;

    for (int k0 = 0; k0 < DM; k0 += 64) {
        __syncthreads();
        #pragma unroll
        for (int t = 0; t < 2; t++) {
            const int i = wave + t * 4;                 // wave-uniform instr index, 8 total
            __builtin_amdgcn_global_load_lds(
                (const gu32*)(const void*)(ga0 + (size_t)i * 16 * DM + k0),
                (lu32*)(void*)(lds_a + i * 1024), 16, 0, 0);
            __builtin_amdgcn_global_load_lds(
                (const gu32*)(const void*)(gb0 + (size_t)i * 16 * DM + k0),
                (lu32*)(void*)(lds_b + i * 1024), 16, 0, 0);
        }
        __syncthreads();
        i32x4 af[4], bfr[4];
        #pragma unroll
        for (int mi = 0; mi < 4; mi++) {
            int r = wr * 64 + mi * 16 + l15;
            af[mi] = *(const i32x4*)&lds_a[r * 64 + quad * 16];
        }
        #pragma unroll
        for (int ni = 0; ni < 4; ni++) {
            int n = wc * 64 + ni * 16 + l15;
            bfr[ni] = *(const i32x4*)&lds_b[n * 64 + quad * 16];
        }
        #pragma unroll
        for (int mi = 0; mi < 4; mi++)
            #pragma unroll
            for (int ni = 0; ni < 4; ni++)
                acc[mi][ni] = __builtin_amdgcn_mfma_i32_16x16x64_i8(af[mi], bfr[ni], acc[mi][ni], 0, 0, 0);
    }

    #pragma unroll
    for (int mi = 0; mi < 4; mi++) {
        int tbase = row0 + wr * 64 + mi * 16 + quad * 4;
        if (mode == 2) {
            int bb = tbase >> 11, n = tbase & 2047;
            int tile = n >> 5, tin = n & 31;
            #pragma unroll
            for (int ni = 0; ni < 4; ni++) {
                int o = col0 + wc * 64 + ni * 16 + l15;
                int hh = o >> 6, dh = o & 63;
                ushort4 hv, lv;
                #pragma unroll
                for (int reg = 0; reg < 4; reg++) {
                    double sa = ascale[tbase + reg] * wsc;
                    float fv = (float)((double)acc[mi][ni][reg] * sa) * prescale;
                    _Float16 hl = (_Float16)fv;
                    _Float16 ml = (_Float16)((fv - (float)hl) * 2048.0f);
                    ((unsigned short*)&hv)[reg] = h16b(hl);
                    ((unsigned short*)&lv)[reg] = h16b(ml);
                }
                size_t idx = (((size_t)(bb * HEADS + hh) * 64 + tile) * 64 + dh) * 32 + tin;
                *(ushort4*)((unsigned short*)outp + idx)           = hv;
                *(ushort4*)((unsigned short*)outp + idx + 4194304) = lv;
            }
        } else {
            #pragma unroll
            for (int reg = 0; reg < 4; reg++) {
                int t = tbase + reg;
                double sa = ascale[t] * wsc;
                #pragma unroll
                for (int ni = 0; ni < 4; ni++) {
                    int o = col0 + wc * 64 + ni * 16 + l15;
                    float val = (float)((double)acc[mi][ni][reg] * sa);
                    if (mode == 1) {
                        ((float*)outp)[(size_t)t * DM + o] = val;
                    } else {
                        int bb = t >> 11, n = t & 2047, hh = o >> 6, dh = o & 63;
                        float fv = val * prescale;
                        _Float16 hl = (_Float16)fv;
                        _Float16 ml = (_Float16)((fv - (float)hl) * 2048.0f);
                        size_t idx = (((size_t)(bb * HEADS + hh) * SEQ + n) << 6) + dh;
                        ((unsigned short*)outp)[idx]           = h16b(hl);
                        ((unsigned short*)outp)[idx + 4194304] = h16b(ml);
                    }
                }
            }
        }
    }
}

// fused Q/K/V projections: 768 blocks = 3/CU co-resident (hides barrier drain)
// Q prescale folds softmax scale AND log2(e): 0.125 * 1.4426950408889634
__global__ __launch_bounds__(256) void gemm_qkv(
        const signed char* __restrict__ xq, const signed char* __restrict__ cq,
        const signed char* __restrict__ wqb, const double* __restrict__ ascale_x,
        const double* __restrict__ wscale, void* __restrict__ qkv) {
    const int which = blockIdx.x >> 3;          // 0=Q, 1=K, 2=V
    char* base = (char*)qkv + (size_t)which * 16777216;
    gemm_core(which == 0 ? xq : cq,
              wqb + (size_t)which * 1048576,
              ascale_x + (which ? NTOK : 0),
              wscale[which],
              base,
              which == 2 ? 2 : 0,
              which == 0 ? 0.18033688011112042f : 1.0f, blockIdx.x & 7, blockIdx.y);
}

__global__ __launch_bounds__(256) void gemm_o(
        const signed char* __restrict__ aq, const signed char* __restrict__ wo,
        const double* __restrict__ ascale, const double* __restrict__ wscale_p,
        float* __restrict__ out) {
    gemm_core(aq, wo, ascale, *wscale_p, out, 1, 1.0f, blockIdx.x, blockIdx.y);
}

// ---------------- MFMA flash attention v9: dbuf single-barrier, V split LDS/L1 ------------
// Model (cyc/tile/CU): MFMA floor 1862/SIMD. v5 all-LDS: LDS 3.1K -> wall 5.3K (141us).
// v8 V-all-L1: L1 2.1K + unhidden latency -> wall 8K (214us). v9 balances:
//  - K (both limbs) + V-hi: LDS, DOUBLE-BUFFERED -> ONE barrier per tile (convoy halved).
//    Stage tile t+1 into buf^1 while computing from buf; barrier at iteration end.
//  - V-lo: per-wave f16x8 frags from fragment-tiled global (1KB contig), reloaded right
//    AFTER PV -> ~a full tile of latency slack, never on the critical path.
//  - K(t+2)/Vhi(t+2) register-prefetched (vmcnt survives the lgkm-only barrier).
//  - s_setprio(1) around MFMA clusters (T5: the 4 unsynced blocks/CU give role diversity).
// Pipes/tile/CU: LDS ~2.1K, L1 ~1.2K, MFMA 1.86K/SIMD, VALU ~1K/SIMD -> no pipe >60%.
#define KH_IDX(row, d8) (((row) * 8 + ((d8) ^ ((row) & 7))) * 8)       // halves
#define VSW(row) (((row) >> 1) & 3)

__global__ __launch_bounds__(256, 4) void attn_mfma(
        const unsigned short* __restrict__ qhg, const unsigned short* __restrict__ qlg,
        const unsigned short* __restrict__ khg, const unsigned short* __restrict__ klg,
        const unsigned short* __restrict__ vhg, const unsigned short* __restrict__ vlg,
        float* __restrict__ out) {
    __shared__ __align__(16) _Float16 KhL[2][32 * 64];
    __shared__ __align__(16) _Float16 KlL[2][32 * 64];
    __shared__ __align__(16) _Float16 VhL[2][64 * 32];   // [dh][t] hi-limb, swizzled chunks
    __shared__ __align__(16) _Float16 PhL[4][16 * 36];   // pad-36 rows: <=2-way banks
    __shared__ __align__(16) _Float16 PlL[4][16 * 36];
    __shared__ float Lp[4][16][4];

    const int lin  = blockIdx.x;
    const int bh   = (lin & 7) * 4 + ((lin >> 3) & 3);   // co-resident blocks share bh
    const int qblk = (lin >> 5) & 31;
    const int tid  = threadIdx.x;
    const int wave = tid >> 6, lane = tid & 63;
    const int l15  = lane & 15, quad = lane >> 4;
    const int qbase = qblk * 64 + wave * 16;

    // ---- Q fragments: direct f16x8 loads from separate limb planes ----
    f16x8 qh[2], qm[2];
    #pragma unroll
    for (int c = 0; c < 2; c++) {
        size_t off = (((size_t)bh * SEQ + qbase + l15) << 6) + c * 32 + quad * 8;
        qh[c] = *(const f16x8*)(qhg + off);
        qm[c] = *(const f16x8*)(qlg + off);
    }

    floatx4 och[4] = {};   // [nh] hi-scale PV acc
    floatx4 ocm[4] = {};   // [nh] 2^-11-scale PV acc
    float lsum = 0.f;

    const unsigned short* khb = khg + ((size_t)bh * SEQ << 6);   // [t][dh] plane
    const unsigned short* klb = klg + ((size_t)bh * SEQ << 6);
    const unsigned short* vhb = vhg + ((size_t)bh << 17);        // fragment-tiled plane
    const unsigned short* vlb = vlg + ((size_t)bh << 17);

    const int kk = tid >> 3, d8 = tid & 7;
    const int vrow = tid >> 2, vc = tid & 3;
    const int vcs  = vc ^ VSW(vrow);

    // ---- prologue: load tile0, stage into buf0; load tile1 into prefetch regs ----
    uint4 kh_pf = *(const uint4*)(khb + ((size_t)kk << 6) + d8 * 8);
    uint4 kl_pf = *(const uint4*)(klb + ((size_t)kk << 6) + d8 * 8);
    uint4 vh_pf = *(const uint4*)(vhb + vrow * 32 + vc * 8);
    f16x8 vlo[4];
    #pragma unroll
    for (int nh = 0; nh < 4; nh++)
        vlo[nh] = *(const f16x8*)(vlb + ((nh * 16 + l15) << 5) + quad * 8);

    *(uint4*)&KhL[0][KH_IDX(kk, d8)] = kh_pf;
    *(uint4*)&KlL[0][KH_IDX(kk, d8)] = kl_pf;
    *(uint4*)&VhL[0][(vrow * 4 + vcs) * 8] = vh_pf;

    kh_pf = *(const uint4*)(khb + ((size_t)(32 + kk) << 6) + d8 * 8);
    kl_pf = *(const uint4*)(klb + ((size_t)(32 + kk) << 6) + d8 * 8);
    vh_pf = *(const uint4*)(vhb + 2048 + vrow * 32 + vc * 8);

    BAR_LGKM();   // buf0 visible to all waves

    for (int t = 0; t < 64; t++) {
        const int cur = t & 1, nxt = cur ^ 1;

        // stage K(t+1)/Vhi(t+1) into the other buffer (no reader conflict: barrier at
        // end of prev iteration guaranteed those reads finished)
        *(uint4*)&KhL[nxt][KH_IDX(kk, d8)] = kh_pf;   // vmcnt wait on t+1 loads (1 tile old)
        *(uint4*)&KlL[nxt][KH_IDX(kk, d8)] = kl_pf;
        *(uint4*)&VhL[nxt][(vrow * 4 + vcs) * 8] = vh_pf;

        // issue loads for tile t+2 (clamped; consumed next iteration's staging)
        {
            const int t2 = (t + 2 < 64) ? t + 2 : 63;
            kh_pf = *(const uint4*)(khb + ((size_t)(t2 * 32 + kk) << 6) + d8 * 8);
            kl_pf = *(const uint4*)(klb + ((size_t)(t2 * 32 + kk) << 6) + d8 * 8);
            vh_pf = *(const uint4*)(vhb + t2 * 2048 + vrow * 32 + vc * 8);
        }

        // K fragments (A-operand) from current buffer
        f16x8 kfh[2][2], kfl[2][2];
        #pragma unroll
        for (int ms = 0; ms < 2; ms++) {
            #pragma unroll
            for (int c = 0; c < 2; c++) {
                kfh[ms][c] = *(const f16x8*)&KhL[cur][KH_IDX(ms * 16 + l15, c * 4 + quad)];
                kfl[ms][c] = *(const f16x8*)&KlL[cur][KH_IDX(ms * 16 + l15, c * 4 + quad)];
            }
        }

        // QK MFMAs
        floatx4 ah[2], am[2];
        __builtin_amdgcn_s_setprio(1);
        #pragma unroll
        for (int ms = 0; ms < 2; ms++) {
            ah[ms] = (floatx4){};
            am[ms] = (floatx4){};
            #pragma unroll
            for (int c = 0; c < 2; c++) {
                ah[ms] = __builtin_amdgcn_mfma_f32_16x16x32_f16(kfh[ms][c], qh[c], ah[ms], 0, 0, 0);
                am[ms] = __builtin_amdgcn_mfma_f32_16x16x32_f16(kfh[ms][c], qm[c], am[ms], 0, 0, 0);
                am[ms] = __builtin_amdgcn_mfma_f32_16x16x32_f16(kfl[ms][c], qh[c], am[ms], 0, 0, 0);
            }
        }
        __builtin_amdgcn_s_setprio(0);

        // softmax: p = exp2(s) -> P limb planes
        #pragma unroll
        for (int ms = 0; ms < 2; ms++) {
            float p[4];
            #pragma unroll
            for (int r = 0; r < 4; r++) {
                float s = ah[ms][r] + am[ms][r] * 4.8828125e-4f;
                p[r] = exp2f(s);
                lsum += p[r];
            }
            f16x4 hv, lv;
            #pragma unroll
            for (int r = 0; r < 4; r++) {
                _Float16 h = (_Float16)p[r];
                hv[r] = h;
                lv[r] = (_Float16)((p[r] - (float)h) * 2048.0f);
            }
            int poff = l15 * 36 + ms * 16 + quad * 4;
            *(f16x4*)&PhL[wave][poff] = hv;
            *(f16x4*)&PlL[wave][poff] = lv;
        }
        WAIT_LGKM();   // P writes visible to own wave's cross-lane reads (vmcnt untouched)

        // P fragments + V-hi fragments from LDS; V-lo already in regs (loaded last iter)
        f16x8 pfh = *(const f16x8*)&PhL[wave][l15 * 36 + quad * 8];
        f16x8 pfm = *(const f16x8*)&PlL[wave][l15 * 36 + quad * 8];
        f16x8 vfh[4];
        #pragma unroll
        for (int nh = 0; nh < 4; nh++) {
            int vro = nh * 16 + l15;
            vfh[nh] = *(const f16x8*)&VhL[cur][(vro * 4 + (quad ^ VSW(vro))) * 8];
        }
        __builtin_amdgcn_s_setprio(1);
        #pragma unroll
        for (int nh = 0; nh < 4; nh++) {
            och[nh] = __builtin_amdgcn_mfma_f32_16x16x32_f16(pfh, vfh[nh], och[nh], 0, 0, 0);
            ocm[nh] = __builtin_amdgcn_mfma_f32_16x16x32_f16(pfh, vlo[nh], ocm[nh], 0, 0, 0);
            ocm[nh] = __builtin_amdgcn_mfma_f32_16x16x32_f16(pfm, vfh[nh], ocm[nh], 0, 0, 0);
        }
        __builtin_amdgcn_s_setprio(0);

        // reload V-lo fragments for tile t+1 (consumed next PV: ~full tile of slack)
        {
            const int t1 = (t + 1 < 64) ? t + 1 : 63;
            #pragma unroll
            for (int nh = 0; nh < 4; nh++)
                vlo[nh] = *(const f16x8*)(vlb + (size_t)t1 * 2048 + ((nh * 16 + l15) << 5) + quad * 8);
        }

        BAR_LGKM();   // single barrier per tile: staged buffers visible, readers drained
    }

    // ---- epilogue: merge l across quads, normalize, write ----
    Lp[wave][l15][quad] = lsum;
    WAIT_LGKM();

    int b = bh >> 4, h = bh & 15;
    float linv[4];
    #pragma unroll
    for (int r = 0; r < 4; r++) {
        float4 lv = *(const float4*)&Lp[wave][quad * 4 + r][0];
        linv[r] = 1.0f / (lv.x + lv.y + lv.z + lv.w);
    }
    #pragma unroll
    for (int nh = 0; nh < 4; nh++) {
        #pragma unroll
        for (int r = 0; r < 4; r++) {
            int token = b * SEQ + qbase + quad * 4 + r;
            float val = (och[nh][r] + ocm[nh][r] * 4.8828125e-4f) * linv[r];
            out[(size_t)token * DM + h * 64 + nh * 16 + l15] = val;
        }
    }
}

extern "C" void kernel_launch(void* const* d_in, const int* in_sizes, int n_in,
                              void* d_out, int out_size, void* d_ws, size_t ws_size,
                              hipStream_t stream) {
    const float* x       = (const float*)d_in[0];
    const float* context = (const float*)d_in[1];
    const float* Wq      = (const float*)d_in[2];
    const float* Wk      = (const float*)d_in[3];
    const float* Wv      = (const float*)d_in[4];
    const float* Wo      = (const float*)d_in[5];
    char* ws = (char*)d_ws;

    // workspace layout (~71.4 MB). Plane region at +21102592:
    //   Qh 8MB | Ql 8MB | Kh 8MB | Kl 8MB | Vh 8MB | Vl 8MB  (48 MB total)
    double* wscale   = (double*)(ws + 0);            // 4 doubles
    double* partial  = (double*)(ws + 4096);         // 256 doubles
    double* ascale_x = (double*)(ws + 8192);         // 8192 doubles (x then ctx)
    double* ascale_a = (double*)(ws + 73728);        // 4096 doubles
    signed char* wqb = (signed char*)(ws + 131072);          // 4 x 1 MB int8
    signed char* xq  = (signed char*)(ws + 4325376);         // 4 MB (cq follows)
    signed char* cq  = (signed char*)(ws + 8519680);         // 4 MB
    float* attn_out  = (float*)(ws + 4325376);               // aliases xq+cq region (16 MB)
    char* planes     = ws + 21102592;                        // 48 MB limb planes
    signed char* aq  = (signed char*)(ws + 21102592);        // aliases Q planes, used after attention

    unsigned short* qhg = (unsigned short*)planes;
    unsigned short* qlg = qhg + 4194304;
    unsigned short* khg = (unsigned short*)(planes + 16777216);
    unsigned short* klg = khg + 4194304;
    unsigned short* vhg = (unsigned short*)(planes + 33554432);
    unsigned short* vlg = vhg + 4194304;

    wsum1<<<dim3(64, 4), 256, 0, stream>>>(Wq, Wk, Wv, Wo, partial);
    wsum2<<<1, 64, 0, stream>>>(partial, wscale);
    wquant<<<dim3(1024, 4), 256, 0, stream>>>(Wq, Wk, Wv, Wo, wscale, wqb);
    aquant2<<<2 * NTOK, 256, 0, stream>>>(x, context, xq, ascale_x);

    gemm_qkv<<<dim3(24, 32), 256, 0, stream>>>(xq, cq, wqb, ascale_x, wscale, planes);

    attn_mfma<<<dim3(1024), 256, 0, stream>>>(qhg, qlg, khg, klg, vhg, vlg, attn_out);

    aquant<<<NTOK, 256, 0, stream>>>(attn_out, aq, ascale_a);
    gemm_o<<<dim3(8, 32), 256, 0, stream>>>(aq, wqb + 3145728, ascale_a, wscale + 3, (float*)d_out);
}

// Round 8
// 294.063 us; speedup vs baseline: 1.4222x; 1.0688x over previous
//
#include <hip/hip_runtime.h>
#include <math.h>

#define HEADS   16
#define DHEAD   64
#define SEQ     2048
#define NB      2
#define DM      1024
#define NTOK    4096           // NB*SEQ
#define WEPS    1e-5

using f16x8   = __attribute__((ext_vector_type(8))) _Float16;
using f16x4   = __attribute__((ext_vector_type(4))) _Float16;
using fp16x2  = __attribute__((ext_vector_type(2))) __fp16;   // cvt_pkrtz result type
using floatx4 = __attribute__((ext_vector_type(4))) float;
using i32x4   = __attribute__((ext_vector_type(4))) int;

typedef __attribute__((address_space(1))) unsigned int gu32;
typedef __attribute__((address_space(3))) unsigned int lu32;

// lgkmcnt(0)-only barrier: does NOT drain vmcnt (register prefetch survives).
// Safe because LDS staging here is plain ds_write (not global_load_lds DMA).
#define BAR_LGKM()  asm volatile("s_waitcnt lgkmcnt(0)\n\ts_barrier" ::: "memory")
#define WAIT_LGKM() asm volatile("s_waitcnt lgkmcnt(0)" ::: "memory")

__device__ __forceinline__ unsigned short h16b(_Float16 h) {
    union { _Float16 h; unsigned short u; } c; c.h = h; return c.u;
}
__device__ __forceinline__ unsigned pk2u(fp16x2 v) {
    union { fp16x2 h; unsigned u; } c; c.h = v; return c.u;
}

// ---------------- weight |w| mean: pass 1 (partial sums in double) ----------------
__global__ void wsum1(const float* __restrict__ w0, const float* __restrict__ w1,
                      const float* __restrict__ w2, const float* __restrict__ w3,
                      double* __restrict__ partial) {
    const float* w = (blockIdx.y == 0) ? w0 : (blockIdx.y == 1) ? w1 : (blockIdx.y == 2) ? w2 : w3;
    int base = blockIdx.x * 16384;
    double s = 0.0;
    for (int i = threadIdx.x; i < 16384; i += 256)
        s += fabs((double)w[base + i]);
    __shared__ double sd[256];
    sd[threadIdx.x] = s;
    __syncthreads();
    for (int st = 128; st > 0; st >>= 1) {
        if (threadIdx.x < st) sd[threadIdx.x] += sd[threadIdx.x + st];
        __syncthreads();
    }
    if (threadIdx.x == 0) partial[blockIdx.y * 64 + blockIdx.x] = sd[0];
}

// ---------------- weight mean: pass 2 -> wscale[w] = clip(mean|w|, eps) ----------------
__global__ void wsum2(const double* __restrict__ partial, double* __restrict__ wscale) {
    int t = threadIdx.x;
    if (t < 4) {
        double s = 0.0;
        for (int i = 0; i < 64; i++) s += partial[t * 64 + i];
        double mean = s / (1024.0 * 1024.0);
        wscale[t] = (mean > WEPS) ? mean : WEPS;
    }
}

// ---------------- ternary weight quant -> int8 {-1,0,1} ----------------
__global__ void wquant(const float* __restrict__ w0, const float* __restrict__ w1,
                       const float* __restrict__ w2, const float* __restrict__ w3,
                       const double* __restrict__ wscale, signed char* __restrict__ wq) {
    int widx = blockIdx.y;
    const float* w = (widx == 0) ? w0 : (widx == 1) ? w1 : (widx == 2) ? w2 : w3;
    double ws = 1.0 / wscale[widx];
    int idx = (blockIdx.x * 256 + threadIdx.x) * 4;
    float4 wv = *(const float4*)(w + idx);
    char4 o;
    {
        double r = rint((double)wv.x * ws); r = r > 1.0 ? 1.0 : (r < -1.0 ? -1.0 : r); o.x = (signed char)r;
    } {
        double r = rint((double)wv.y * ws); r = r > 1.0 ? 1.0 : (r < -1.0 ? -1.0 : r); o.y = (signed char)r;
    } {
        double r = rint((double)wv.z * ws); r = r > 1.0 ? 1.0 : (r < -1.0 ? -1.0 : r); o.z = (signed char)r;
    } {
        double r = rint((double)wv.w * ws); r = r > 1.0 ? 1.0 : (r < -1.0 ? -1.0 : r); o.w = (signed char)r;
    }
    *(char4*)(wq + (size_t)widx * 1048576 + idx) = o;
}

// ---------------- per-token int8 absmax activation quant -> int8 ----------------
__device__ __forceinline__ void aquant_row(const float* __restrict__ row,
                                           signed char* __restrict__ dst_row,
                                           double* __restrict__ ascale_p) {
    int t = threadIdx.x;
    float4 xv = *(const float4*)(row + t * 4);
    float a = fmaxf(fmaxf(fabsf(xv.x), fabsf(xv.y)), fmaxf(fabsf(xv.z), fabsf(xv.w)));
    __shared__ float sm[256];
    sm[t] = a;
    __syncthreads();
    for (int st = 128; st > 0; st >>= 1) {
        if (t < st) sm[t] = fmaxf(sm[t], sm[t + st]);
        __syncthreads();
    }
    double mx = (double)sm[0];
    if (mx < WEPS) mx = WEPS;
    if (t == 0) *ascale_p = mx / 127.0;
    double xs = 127.0 / mx;
    char4 o;
    {
        double r = rint((double)xv.x * xs); r = r > 127.0 ? 127.0 : (r < -128.0 ? -128.0 : r); o.x = (signed char)r;
    } {
        double r = rint((double)xv.y * xs); r = r > 127.0 ? 127.0 : (r < -128.0 ? -128.0 : r); o.y = (signed char)r;
    } {
        double r = rint((double)xv.z * xs); r = r > 127.0 ? 127.0 : (r < -128.0 ? -128.0 : r); o.z = (signed char)r;
    } {
        double r = rint((double)xv.w * xs); r = r > 127.0 ? 127.0 : (r < -128.0 ? -128.0 : r); o.w = (signed char)r;
    }
    *(char4*)(dst_row + t * 4) = o;
}

__global__ void aquant(const float* __restrict__ src, signed char* __restrict__ dst,
                       double* __restrict__ ascale) {
    int tok = blockIdx.x;
    aquant_row(src + (size_t)tok * DM, dst + (size_t)tok * DM, ascale + tok);
}

// fused x + context quant: xq/cq and ascale_x/ascale_c are contiguous in ws
__global__ void aquant2(const float* __restrict__ x, const float* __restrict__ ctx,
                        signed char* __restrict__ dst, double* __restrict__ ascale) {
    int tok = blockIdx.x;
    const float* row = (tok < NTOK) ? x + (size_t)tok * DM : ctx + (size_t)(tok - NTOK) * DM;
    aquant_row(row, dst + (size_t)tok * DM, ascale + tok);
}

// ---------------- int8 MFMA GEMM core: C[m][n] = sum_k A[m][k]*W[n][k], exact i32 ----------
// m97 structure: async global_load_lds width-16 staging, 128x128 tile, BK=64.
// mode 0 (Q,K): separate hi/lo f16 limb planes at [b][h][t][dh] (lo at +4194304 elems)
// mode 2 (V):   separate limb planes, V transposed [b][h][dh][t]; 4 consecutive t are
//               in-lane (reg idx) -> vectorized ushort4 stores (4x fewer store instrs)
// mode 1: plain fp32 [t][o].
__device__ __forceinline__ void gemm_core(
        const signed char* __restrict__ A, const signed char* __restrict__ W,
        const double* __restrict__ ascale, double wsc,
        void* __restrict__ outp, int mode, float prescale, int bx, int by) {
    __shared__ __align__(16) signed char lds_a[128 * 64];
    __shared__ __align__(16) signed char lds_b[128 * 64];
    const int tid  = threadIdx.x;
    const int wave = tid >> 6, lane = tid & 63;
    const int wr = wave >> 1, wc = wave & 1;
    const int quad = lane >> 4, l15 = lane & 15;
    const int row0 = by * 128, col0 = bx * 128;
    i32x4 acc[4][4] = {};

    const signed char* ga0 = A + (size_t)(row0 + (lane >> 2)) * DM + (lane & 3) * 16;
    const signed char* gb0 = W + (size_t)(col0 + (lane >> 2)) * DM + (lane & 3) * 16;

    for (int k0 = 0; k0 < DM; k0 += 64) {
        __syncthreads();
        #pragma unroll
        for (int t = 0; t < 2; t++) {
            const int i = wave + t * 4;                 // wave-uniform instr index, 8 total
            __builtin_amdgcn_global_load_lds(
                (const gu32*)(const void*)(ga0 + (size_t)i * 16 * DM + k0),
                (lu32*)(void*)(lds_a + i * 1024), 16, 0, 0);
            __builtin_amdgcn_global_load_lds(
                (const gu32*)(const void*)(gb0 + (size_t)i * 16 * DM + k0),
                (lu32*)(void*)(lds_b + i * 1024), 16, 0, 0);
        }
        __syncthreads();
        i32x4 af[4], bfr[4];
        #pragma unroll
        for (int mi = 0; mi < 4; mi++) {
            int r = wr * 64 + mi * 16 + l15;
            af[mi] = *(const i32x4*)&lds_a[r * 64 + quad * 16];
        }
        #pragma unroll
        for (int ni = 0; ni < 4; ni++) {
            int n = wc * 64 + ni * 16 + l15;
            bfr[ni] = *(const i32x4*)&lds_b[n * 64 + quad * 16];
        }
        #pragma unroll
        for (int mi = 0; mi < 4; mi++)
            #pragma unroll
            for (int ni = 0; ni < 4; ni++)
                acc[mi][ni] = __builtin_amdgcn_mfma_i32_16x16x64_i8(af[mi], bfr[ni], acc[mi][ni], 0, 0, 0);
    }

    #pragma unroll
    for (int mi = 0; mi < 4; mi++) {
        int tbase = row0 + wr * 64 + mi * 16 + quad * 4;
        if (mode == 2) {
            int bb = tbase >> 11, n = tbase & 2047;
            #pragma unroll
            for (int ni = 0; ni < 4; ni++) {
                int o = col0 + wc * 64 + ni * 16 + l15;
                int hh = o >> 6, dh = o & 63;
                ushort4 hv, lv;
                #pragma unroll
                for (int reg = 0; reg < 4; reg++) {
                    double sa = ascale[tbase + reg] * wsc;
                    float fv = (float)((double)acc[mi][ni][reg] * sa) * prescale;
                    _Float16 hl = (_Float16)fv;
                    _Float16 ml = (_Float16)((fv - (float)hl) * 2048.0f);
                    ((unsigned short*)&hv)[reg] = h16b(hl);
                    ((unsigned short*)&lv)[reg] = h16b(ml);
                }
                size_t idx = (((size_t)(bb * HEADS + hh) * 64 + dh) << 11) + n;
                *(ushort4*)((unsigned short*)outp + idx)           = hv;
                *(ushort4*)((unsigned short*)outp + idx + 4194304) = lv;
            }
        } else {
            #pragma unroll
            for (int reg = 0; reg < 4; reg++) {
                int t = tbase + reg;
                double sa = ascale[t] * wsc;
                #pragma unroll
                for (int ni = 0; ni < 4; ni++) {
                    int o = col0 + wc * 64 + ni * 16 + l15;
                    float val = (float)((double)acc[mi][ni][reg] * sa);
                    if (mode == 1) {
                        ((float*)outp)[(size_t)t * DM + o] = val;
                    } else {
                        int bb = t >> 11, n = t & 2047, hh = o >> 6, dh = o & 63;
                        float fv = val * prescale;
                        _Float16 hl = (_Float16)fv;
                        _Float16 ml = (_Float16)((fv - (float)hl) * 2048.0f);
                        size_t idx = (((size_t)(bb * HEADS + hh) * SEQ + n) << 6) + dh;
                        ((unsigned short*)outp)[idx]           = h16b(hl);
                        ((unsigned short*)outp)[idx + 4194304] = h16b(ml);
                    }
                }
            }
        }
    }
}

// fused Q/K/V projections: 768 blocks = 3/CU co-resident (hides barrier drain)
// Q prescale folds softmax scale AND log2(e): 0.125 * 1.4426950408889634
__global__ __launch_bounds__(256) void gemm_qkv(
        const signed char* __restrict__ xq, const signed char* __restrict__ cq,
        const signed char* __restrict__ wqb, const double* __restrict__ ascale_x,
        const double* __restrict__ wscale, void* __restrict__ qkv) {
    const int which = blockIdx.x >> 3;          // 0=Q, 1=K, 2=V
    char* base = (char*)qkv + (size_t)which * 16777216;
    gemm_core(which == 0 ? xq : cq,
              wqb + (size_t)which * 1048576,
              ascale_x + (which ? NTOK : 0),
              wscale[which],
              base,
              which == 2 ? 2 : 0,
              which == 0 ? 0.18033688011112042f : 1.0f, blockIdx.x & 7, blockIdx.y);
}

__global__ __launch_bounds__(256) void gemm_o(
        const signed char* __restrict__ aq, const signed char* __restrict__ wo,
        const double* __restrict__ ascale, const double* __restrict__ wscale_p,
        float* __restrict__ out) {
    gemm_core(aq, wo, ascale, *wscale_p, out, 1, 1.0f, blockIdx.x, blockIdx.y);
}

// ---------------- MFMA flash attention v10: v5 structure + instruction diet ---------------
// Invariant across v5-v9: VALU-busy ~69us and MFMA-busy ~46us are structure-independent;
// v5 overlaps them best (82% combined issue) -> v5 is issue-bound on a FIXED instr stream.
// v10 keeps v5's schedule exactly and shrinks the stream:
//  - __builtin_amdgcn_exp2f: single v_exp_f32 (libm exp2f carries range-check cndmasks)
//  - v_cvt_pkrtz packed f32->2xf16 for BOTH P limbs (~25 -> ~16 VALU per 4-value group;
//    RTZ hi-limb residual stays in [0, ulp), captured exactly by the x2048 lo limb)
//  - hoisted zero-quad for QK acc init (kills 16 v_mov/tile)
//  - s_setprio(1) around MFMA clusters (T5: 4 unsynced blocks/CU give role diversity)
#define KH_IDX(row, d8) (((row) * 8 + ((d8) ^ ((row) & 7))) * 8)       // halves
#define VSW(row) (((row) >> 1) & 3)

__global__ __launch_bounds__(256, 4) void attn_mfma(
        const unsigned short* __restrict__ qhg, const unsigned short* __restrict__ qlg,
        const unsigned short* __restrict__ khg, const unsigned short* __restrict__ klg,
        const unsigned short* __restrict__ vhg, const unsigned short* __restrict__ vlg,
        float* __restrict__ out) {
    __shared__ __align__(16) _Float16 KhL[32 * 64];
    __shared__ __align__(16) _Float16 KlL[32 * 64];
    __shared__ __align__(16) _Float16 VhL[64 * 32];      // [dh][t] hi-limb plane
    __shared__ __align__(16) _Float16 VlL[64 * 32];      // [dh][t] lo-limb plane
    __shared__ __align__(16) _Float16 PhL[4][16 * 36];   // pad-36 rows: <=2-way banks
    __shared__ __align__(16) _Float16 PlL[4][16 * 36];
    __shared__ float Lp[4][16][4];

    const int lin  = blockIdx.x;
    const int bh   = (lin & 7) * 4 + (lin >> 8);         // XCD-grouped bh
    const int qblk = (lin >> 3) & 31;
    const int tid  = threadIdx.x;
    const int wave = tid >> 6, lane = tid & 63;
    const int l15  = lane & 15, quad = lane >> 4;
    const int qbase = qblk * 64 + wave * 16;

    // ---- Q fragments: direct f16x8 loads from separate limb planes ----
    f16x8 qh[2], qm[2];
    #pragma unroll
    for (int c = 0; c < 2; c++) {
        size_t off = (((size_t)bh * SEQ + qbase + l15) << 6) + c * 32 + quad * 8;
        qh[c] = *(const f16x8*)(qhg + off);
        qm[c] = *(const f16x8*)(qlg + off);
    }

    floatx4 och[4] = {};   // [nh] hi-scale PV acc
    floatx4 ocm[4] = {};   // [nh] 2^-11-scale PV acc
    float lsum = 0.f;
    const floatx4 zf = {}; // shared zero quad for QK acc init

    const unsigned short* khb = khg + ((size_t)bh * SEQ << 6);
    const unsigned short* klb = klg + ((size_t)bh * SEQ << 6);
    const unsigned short* vhb = vhg + ((size_t)bh << 17);  // [64][2048] halves for this bh
    const unsigned short* vlb = vlg + ((size_t)bh << 17);

    const int kk = tid >> 3, d8 = tid & 7;
    // V staging geometry: lane owns row dh=tid>>2, content-chunk vc=tid&3 (8 t-halves),
    // stored at swizzled chunk position vc^VSW(row): 2-way banks (free, m136).
    const int vrow = tid >> 2, vc = tid & 3;
    const int vcs  = vc ^ VSW(vrow);
    const unsigned short* vsh = vhb + ((size_t)vrow << 11) + vc * 8;
    const unsigned short* vsl = vlb + ((size_t)vrow << 11) + vc * 8;

    // prologue: prefetch K/V tile 0 into regs
    uint4 kh_pf = *(const uint4*)(khb + ((size_t)kk << 6) + d8 * 8);
    uint4 kl_pf = *(const uint4*)(klb + ((size_t)kk << 6) + d8 * 8);
    uint4 vh_pf = *(const uint4*)(vsh);
    uint4 vl_pf = *(const uint4*)(vsl);

    for (int kt = 0; kt < SEQ; kt += 32) {
        BAR_LGKM();   // LDS reads from previous tile done (no vmcnt drain)

        *(uint4*)&KhL[KH_IDX(kk, d8)] = kh_pf;   // auto vmcnt wait on prefetch regs only
        *(uint4*)&KlL[KH_IDX(kk, d8)] = kl_pf;
        *(uint4*)&VhL[(vrow * 4 + vcs) * 8] = vh_pf;
        *(uint4*)&VlL[(vrow * 4 + vcs) * 8] = vl_pf;

        if (kt + 32 < SEQ) {   // prefetch K/V(t+1): full tile of latency tolerance
            kh_pf = *(const uint4*)(khb + ((size_t)(kt + 32 + kk) << 6) + d8 * 8);
            kl_pf = *(const uint4*)(klb + ((size_t)(kt + 32 + kk) << 6) + d8 * 8);
            vh_pf = *(const uint4*)(vsh + kt + 32);
            vl_pf = *(const uint4*)(vsl + kt + 32);
        }

        BAR_LGKM();   // staged K/V visible

        // K fragments (A-operand), direct f16x8 from LDS
        f16x8 kfh[2][2], kfl[2][2];
        #pragma unroll
        for (int ms = 0; ms < 2; ms++) {
            #pragma unroll
            for (int c = 0; c < 2; c++) {
                kfh[ms][c] = *(const f16x8*)&KhL[KH_IDX(ms * 16 + l15, c * 4 + quad)];
                kfl[ms][c] = *(const f16x8*)&KlL[KH_IDX(ms * 16 + l15, c * 4 + quad)];
            }
        }

        // QK -> p = exp2(s) -> P limb planes
        __builtin_amdgcn_s_setprio(1);
        floatx4 ah[2], am[2];
        #pragma unroll
        for (int ms = 0; ms < 2; ms++) {
            ah[ms] = __builtin_amdgcn_mfma_f32_16x16x32_f16(kfh[ms][0], qh[0], zf, 0, 0, 0);
            am[ms] = __builtin_amdgcn_mfma_f32_16x16x32_f16(kfh[ms][0], qm[0], zf, 0, 0, 0);
            am[ms] = __builtin_amdgcn_mfma_f32_16x16x32_f16(kfl[ms][0], qh[0], am[ms], 0, 0, 0);
            ah[ms] = __builtin_amdgcn_mfma_f32_16x16x32_f16(kfh[ms][1], qh[1], ah[ms], 0, 0, 0);
            am[ms] = __builtin_amdgcn_mfma_f32_16x16x32_f16(kfh[ms][1], qm[1], am[ms], 0, 0, 0);
            am[ms] = __builtin_amdgcn_mfma_f32_16x16x32_f16(kfl[ms][1], qh[1], am[ms], 0, 0, 0);
        }
        __builtin_amdgcn_s_setprio(0);

        #pragma unroll
        for (int ms = 0; ms < 2; ms++) {
            float p0 = __builtin_amdgcn_exp2f(ah[ms][0] + am[ms][0] * 4.8828125e-4f);
            float p1 = __builtin_amdgcn_exp2f(ah[ms][1] + am[ms][1] * 4.8828125e-4f);
            float p2 = __builtin_amdgcn_exp2f(ah[ms][2] + am[ms][2] * 4.8828125e-4f);
            float p3 = __builtin_amdgcn_exp2f(ah[ms][3] + am[ms][3] * 4.8828125e-4f);
            lsum += (p0 + p1) + (p2 + p3);
            fp16x2 h01 = __builtin_amdgcn_cvt_pkrtz(p0, p1);
            fp16x2 h23 = __builtin_amdgcn_cvt_pkrtz(p2, p3);
            fp16x2 m01 = __builtin_amdgcn_cvt_pkrtz((p0 - (float)h01[0]) * 2048.0f,
                                                    (p1 - (float)h01[1]) * 2048.0f);
            fp16x2 m23 = __builtin_amdgcn_cvt_pkrtz((p2 - (float)h23[0]) * 2048.0f,
                                                    (p3 - (float)h23[1]) * 2048.0f);
            int poff = l15 * 36 + ms * 16 + quad * 4;
            *(uint2*)&PhL[wave][poff] = make_uint2(pk2u(h01), pk2u(h23));
            *(uint2*)&PlL[wave][poff] = make_uint2(pk2u(m01), pk2u(m23));
        }
        WAIT_LGKM();   // P writes visible to own wave's cross-lane reads

        // P fragments (A-operand) + V limb-plane fragments (B-operand) straight from LDS
        f16x8 pfh = *(const f16x8*)&PhL[wave][l15 * 36 + quad * 8];
        f16x8 pfm = *(const f16x8*)&PlL[wave][l15 * 36 + quad * 8];
        __builtin_amdgcn_s_setprio(1);
        #pragma unroll
        for (int nh = 0; nh < 4; nh++) {
            int vro = nh * 16 + l15;
            int vof = (vro * 4 + (quad ^ VSW(vro))) * 8;
            f16x8 vfh = *(const f16x8*)&VhL[vof];
            f16x8 vfm = *(const f16x8*)&VlL[vof];
            och[nh] = __builtin_amdgcn_mfma_f32_16x16x32_f16(pfh, vfh, och[nh], 0, 0, 0);
            ocm[nh] = __builtin_amdgcn_mfma_f32_16x16x32_f16(pfh, vfm, ocm[nh], 0, 0, 0);
            ocm[nh] = __builtin_amdgcn_mfma_f32_16x16x32_f16(pfm, vfh, ocm[nh], 0, 0, 0);
        }
        __builtin_amdgcn_s_setprio(0);
    }

    // ---- epilogue: merge l across quads, normalize, write ----
    Lp[wave][l15][quad] = lsum;
    WAIT_LGKM();

    int b = bh >> 4, h = bh & 15;
    float linv[4];
    #pragma unroll
    for (int r = 0; r < 4; r++) {
        float4 lv = *(const float4*)&Lp[wave][quad * 4 + r][0];
        linv[r] = 1.0f / (lv.x + lv.y + lv.z + lv.w);
    }
    #pragma unroll
    for (int nh = 0; nh < 4; nh++) {
        #pragma unroll
        for (int r = 0; r < 4; r++) {
            int token = b * SEQ + qbase + quad * 4 + r;
            float val = (och[nh][r] + ocm[nh][r] * 4.8828125e-4f) * linv[r];
            out[(size_t)token * DM + h * 64 + nh * 16 + l15] = val;
        }
    }
}

extern "C" void kernel_launch(void* const* d_in, const int* in_sizes, int n_in,
                              void* d_out, int out_size, void* d_ws, size_t ws_size,
                              hipStream_t stream) {
    const float* x       = (const float*)d_in[0];
    const float* context = (const float*)d_in[1];
    const float* Wq      = (const float*)d_in[2];
    const float* Wk      = (const float*)d_in[3];
    const float* Wv      = (const float*)d_in[4];
    const float* Wo      = (const float*)d_in[5];
    char* ws = (char*)d_ws;

    // workspace layout (~71.4 MB). Plane region at +21102592:
    //   Qh 8MB | Ql 8MB | Kh 8MB | Kl 8MB | Vh 8MB | Vl 8MB  (48 MB total)
    double* wscale   = (double*)(ws + 0);            // 4 doubles
    double* partial  = (double*)(ws + 4096);         // 256 doubles
    double* ascale_x = (double*)(ws + 8192);         // 8192 doubles (x then ctx)
    double* ascale_a = (double*)(ws + 73728);        // 4096 doubles
    signed char* wqb = (signed char*)(ws + 131072);          // 4 x 1 MB int8
    signed char* xq  = (signed char*)(ws + 4325376);         // 4 MB (cq follows)
    signed char* cq  = (signed char*)(ws + 8519680);         // 4 MB
    float* attn_out  = (float*)(ws + 4325376);               // aliases xq+cq region (16 MB)
    char* planes     = ws + 21102592;                        // 48 MB limb planes
    signed char* aq  = (signed char*)(ws + 21102592);        // aliases Q planes, used after attention

    unsigned short* qhg = (unsigned short*)planes;
    unsigned short* qlg = qhg + 4194304;
    unsigned short* khg = (unsigned short*)(planes + 16777216);
    unsigned short* klg = khg + 4194304;
    unsigned short* vhg = (unsigned short*)(planes + 33554432);
    unsigned short* vlg = vhg + 4194304;

    wsum1<<<dim3(64, 4), 256, 0, stream>>>(Wq, Wk, Wv, Wo, partial);
    wsum2<<<1, 64, 0, stream>>>(partial, wscale);
    wquant<<<dim3(1024, 4), 256, 0, stream>>>(Wq, Wk, Wv, Wo, wscale, wqb);
    aquant2<<<2 * NTOK, 256, 0, stream>>>(x, context, xq, ascale_x);

    gemm_qkv<<<dim3(24, 32), 256, 0, stream>>>(xq, cq, wqb, ascale_x, wscale, planes);

    attn_mfma<<<dim3(1024), 256, 0, stream>>>(qhg, qlg, khg, klg, vhg, vlg, attn_out);

    aquant<<<NTOK, 256, 0, stream>>>(attn_out, aq, ascale_a);
    gemm_o<<<dim3(8, 32), 256, 0, stream>>>(aq, wqb + 3145728, ascale_a, wscale + 3, (float*)d_out);
}

// Round 9
// 269.771 us; speedup vs baseline: 1.5503x; 1.0900x over previous
//
#include <hip/hip_runtime.h>
#include <math.h>

#define HEADS   16
#define DHEAD   64
#define SEQ     2048
#define NB      2
#define DM      1024
#define NTOK    4096           // NB*SEQ
#define WEPS    1e-5

using f16x8   = __attribute__((ext_vector_type(8))) _Float16;
using f16x4   = __attribute__((ext_vector_type(4))) _Float16;
using fp16x2  = __attribute__((ext_vector_type(2))) __fp16;   // cvt_pkrtz result type
using floatx4 = __attribute__((ext_vector_type(4))) float;
using i32x4   = __attribute__((ext_vector_type(4))) int;

typedef __attribute__((address_space(1))) unsigned int gu32;
typedef __attribute__((address_space(3))) unsigned int lu32;

// lgkmcnt(0)-only barrier: does NOT drain vmcnt (register prefetch survives).
// Safe because LDS staging here is plain ds_write (not global_load_lds DMA).
#define BAR_LGKM()  asm volatile("s_waitcnt lgkmcnt(0)\n\ts_barrier" ::: "memory")
#define WAIT_LGKM() asm volatile("s_waitcnt lgkmcnt(0)" ::: "memory")

__device__ __forceinline__ unsigned short h16b(_Float16 h) {
    union { _Float16 h; unsigned short u; } c; c.h = h; return c.u;
}
__device__ __forceinline__ unsigned pk2u(fp16x2 v) {
    union { fp16x2 h; unsigned u; } c; c.h = v; return c.u;
}

// ---------------- weight |w| mean: pass 1 (partial sums in double) ----------------
__global__ void wsum1(const float* __restrict__ w0, const float* __restrict__ w1,
                      const float* __restrict__ w2, const float* __restrict__ w3,
                      double* __restrict__ partial) {
    const float* w = (blockIdx.y == 0) ? w0 : (blockIdx.y == 1) ? w1 : (blockIdx.y == 2) ? w2 : w3;
    int base = blockIdx.x * 16384;
    double s = 0.0;
    for (int i = threadIdx.x; i < 16384; i += 256)
        s += fabs((double)w[base + i]);
    __shared__ double sd[256];
    sd[threadIdx.x] = s;
    __syncthreads();
    for (int st = 128; st > 0; st >>= 1) {
        if (threadIdx.x < st) sd[threadIdx.x] += sd[threadIdx.x + st];
        __syncthreads();
    }
    if (threadIdx.x == 0) partial[blockIdx.y * 64 + blockIdx.x] = sd[0];
}

// ---------------- weight mean: pass 2 -> wscale[w] = clip(mean|w|, eps) ----------------
__global__ void wsum2(const double* __restrict__ partial, double* __restrict__ wscale) {
    int t = threadIdx.x;
    if (t < 4) {
        double s = 0.0;
        for (int i = 0; i < 64; i++) s += partial[t * 64 + i];
        double mean = s / (1024.0 * 1024.0);
        wscale[t] = (mean > WEPS) ? mean : WEPS;
    }
}

// ---------------- ternary weight quant -> int8 {-1,0,1} ----------------
__global__ void wquant(const float* __restrict__ w0, const float* __restrict__ w1,
                       const float* __restrict__ w2, const float* __restrict__ w3,
                       const double* __restrict__ wscale, signed char* __restrict__ wq) {
    int widx = blockIdx.y;
    const float* w = (widx == 0) ? w0 : (widx == 1) ? w1 : (widx == 2) ? w2 : w3;
    double ws = 1.0 / wscale[widx];
    int idx = (blockIdx.x * 256 + threadIdx.x) * 4;
    float4 wv = *(const float4*)(w + idx);
    char4 o;
    {
        double r = rint((double)wv.x * ws); r = r > 1.0 ? 1.0 : (r < -1.0 ? -1.0 : r); o.x = (signed char)r;
    } {
        double r = rint((double)wv.y * ws); r = r > 1.0 ? 1.0 : (r < -1.0 ? -1.0 : r); o.y = (signed char)r;
    } {
        double r = rint((double)wv.z * ws); r = r > 1.0 ? 1.0 : (r < -1.0 ? -1.0 : r); o.z = (signed char)r;
    } {
        double r = rint((double)wv.w * ws); r = r > 1.0 ? 1.0 : (r < -1.0 ? -1.0 : r); o.w = (signed char)r;
    }
    *(char4*)(wq + (size_t)widx * 1048576 + idx) = o;
}

// ---------------- per-token int8 absmax activation quant -> int8 ----------------
__device__ __forceinline__ void aquant_row(const float* __restrict__ row,
                                           signed char* __restrict__ dst_row,
                                           double* __restrict__ ascale_p) {
    int t = threadIdx.x;
    float4 xv = *(const float4*)(row + t * 4);
    float a = fmaxf(fmaxf(fabsf(xv.x), fabsf(xv.y)), fmaxf(fabsf(xv.z), fabsf(xv.w)));
    __shared__ float sm[256];
    sm[t] = a;
    __syncthreads();
    for (int st = 128; st > 0; st >>= 1) {
        if (t < st) sm[t] = fmaxf(sm[t], sm[t + st]);
        __syncthreads();
    }
    double mx = (double)sm[0];
    if (mx < WEPS) mx = WEPS;
    if (t == 0) *ascale_p = mx / 127.0;
    double xs = 127.0 / mx;
    char4 o;
    {
        double r = rint((double)xv.x * xs); r = r > 127.0 ? 127.0 : (r < -128.0 ? -128.0 : r); o.x = (signed char)r;
    } {
        double r = rint((double)xv.y * xs); r = r > 127.0 ? 127.0 : (r < -128.0 ? -128.0 : r); o.y = (signed char)r;
    } {
        double r = rint((double)xv.z * xs); r = r > 127.0 ? 127.0 : (r < -128.0 ? -128.0 : r); o.z = (signed char)r;
    } {
        double r = rint((double)xv.w * xs); r = r > 127.0 ? 127.0 : (r < -128.0 ? -128.0 : r); o.w = (signed char)r;
    }
    *(char4*)(dst_row + t * 4) = o;
}

__global__ void aquant(const float* __restrict__ src, signed char* __restrict__ dst,
                       double* __restrict__ ascale) {
    int tok = blockIdx.x;
    aquant_row(src + (size_t)tok * DM, dst + (size_t)tok * DM, ascale + tok);
}

// fused x + context quant: xq/cq and ascale_x/ascale_c are contiguous in ws
__global__ void aquant2(const float* __restrict__ x, const float* __restrict__ ctx,
                        signed char* __restrict__ dst, double* __restrict__ ascale) {
    int tok = blockIdx.x;
    const float* row = (tok < NTOK) ? x + (size_t)tok * DM : ctx + (size_t)(tok - NTOK) * DM;
    aquant_row(row, dst + (size_t)tok * DM, ascale + tok);
}

// ---------------- int8 MFMA GEMM core: C[m][n] = sum_k A[m][k]*W[n][k], exact i32 ----------
// m97 structure: async global_load_lds width-16 staging, 128x128 tile, BK=64.
// mode 0 (Q,K): separate hi/lo f16 limb planes at [b][h][t][dh] (lo at +4194304 elems)
// mode 2 (V):   separate limb planes, transposed+FRAGMENT-TILED [b][h][t/32][dh][t%32]
//               -> attn V-fragment f16x8 load is 1KB contiguous; ushort4 stores over t%32
// mode 1: plain fp32 [t][o].
__device__ __forceinline__ void gemm_core(
        const signed char* __restrict__ A, const signed char* __restrict__ W,
        const double* __restrict__ ascale, double wsc,
        void* __restrict__ outp, int mode, float prescale, int bx, int by) {
    __shared__ __align__(16) signed char lds_a[128 * 64];
    __shared__ __align__(16) signed char lds_b[128 * 64];
    const int tid  = threadIdx.x;
    const int wave = tid >> 6, lane = tid & 63;
    const int wr = wave >> 1, wc = wave & 1;
    const int quad = lane >> 4, l15 = lane & 15;
    const int row0 = by * 128, col0 = bx * 128;
    i32x4 acc[4][4] = {};

    const signed char* ga0 = A + (size_t)(row0 + (lane >> 2)) * DM + (lane & 3) * 16;
    const signed char* gb0 = W + (size_t)(col0 + (lane >> 2)) * DM + (lane & 3) * 16;

    for (int k0 = 0; k0 < DM; k0 += 64) {
        __syncthreads();
        #pragma unroll
        for (int t = 0; t < 2; t++) {
            const int i = wave + t * 4;                 // wave-uniform instr index, 8 total
            __builtin_amdgcn_global_load_lds(
                (const gu32*)(const void*)(ga0 + (size_t)i * 16 * DM + k0),
                (lu32*)(void*)(lds_a + i * 1024), 16, 0, 0);
            __builtin_amdgcn_global_load_lds(
                (const gu32*)(const void*)(gb0 + (size_t)i * 16 * DM + k0),
                (lu32*)(void*)(lds_b + i * 1024), 16, 0, 0);
        }
        __syncthreads();
        i32x4 af[4], bfr[4];
        #pragma unroll
        for (int mi = 0; mi < 4; mi++) {
            int r = wr * 64 + mi * 16 + l15;
            af[mi] = *(const i32x4*)&lds_a[r * 64 + quad * 16];
        }
        #pragma unroll
        for (int ni = 0; ni < 4; ni++) {
            int n = wc * 64 + ni * 16 + l15;
            bfr[ni] = *(const i32x4*)&lds_b[n * 64 + quad * 16];
        }
        #pragma unroll
        for (int mi = 0; mi < 4; mi++)
            #pragma unroll
            for (int ni = 0; ni < 4; ni++)
                acc[mi][ni] = __builtin_amdgcn_mfma_i32_16x16x64_i8(af[mi], bfr[ni], acc[mi][ni], 0, 0, 0);
    }

    #pragma unroll
    for (int mi = 0; mi < 4; mi++) {
        int tbase = row0 + wr * 64 + mi * 16 + quad * 4;
        if (mode == 2) {
            int bb = tbase >> 11, n = tbase & 2047;
            int tile = n >> 5, tin = n & 31;
            #pragma unroll
            for (int ni = 0; ni < 4; ni++) {
                int o = col0 + wc * 64 + ni * 16 + l15;
                int hh = o >> 6, dh = o & 63;
                ushort4 hv, lv;
                #pragma unroll
                for (int reg = 0; reg < 4; reg++) {
                    double sa = ascale[tbase + reg] * wsc;
                    float fv = (float)((double)acc[mi][ni][reg] * sa) * prescale;
                    _Float16 hl = (_Float16)fv;
                    _Float16 ml = (_Float16)((fv - (float)hl) * 2048.0f);
                    ((unsigned short*)&hv)[reg] = h16b(hl);
                    ((unsigned short*)&lv)[reg] = h16b(ml);
                }
                size_t idx = (((size_t)(bb * HEADS + hh) * 64 + tile) * 64 + dh) * 32 + tin;
                *(ushort4*)((unsigned short*)outp + idx)           = hv;
                *(ushort4*)((unsigned short*)outp + idx + 4194304) = lv;
            }
        } else {
            #pragma unroll
            for (int reg = 0; reg < 4; reg++) {
                int t = tbase + reg;
                double sa = ascale[t] * wsc;
                #pragma unroll
                for (int ni = 0; ni < 4; ni++) {
                    int o = col0 + wc * 64 + ni * 16 + l15;
                    float val = (float)((double)acc[mi][ni][reg] * sa);
                    if (mode == 1) {
                        ((float*)outp)[(size_t)t * DM + o] = val;
                    } else {
                        int bb = t >> 11, n = t & 2047, hh = o >> 6, dh = o & 63;
                        float fv = val * prescale;
                        _Float16 hl = (_Float16)fv;
                        _Float16 ml = (_Float16)((fv - (float)hl) * 2048.0f);
                        size_t idx = (((size_t)(bb * HEADS + hh) * SEQ + n) << 6) + dh;
                        ((unsigned short*)outp)[idx]           = h16b(hl);
                        ((unsigned short*)outp)[idx + 4194304] = h16b(ml);
                    }
                }
            }
        }
    }
}

// fused Q/K/V projections: 768 blocks = 3/CU co-resident (hides barrier drain)
// Q prescale folds softmax scale AND log2(e): 0.125 * 1.4426950408889634
__global__ __launch_bounds__(256) void gemm_qkv(
        const signed char* __restrict__ xq, const signed char* __restrict__ cq,
        const signed char* __restrict__ wqb, const double* __restrict__ ascale_x,
        const double* __restrict__ wscale, void* __restrict__ qkv) {
    const int which = blockIdx.x >> 3;          // 0=Q, 1=K, 2=V
    char* base = (char*)qkv + (size_t)which * 16777216;
    gemm_core(which == 0 ? xq : cq,
              wqb + (size_t)which * 1048576,
              ascale_x + (which ? NTOK : 0),
              wscale[which],
              base,
              which == 2 ? 2 : 0,
              which == 0 ? 0.18033688011112042f : 1.0f, blockIdx.x & 7, blockIdx.y);
}

__global__ __launch_bounds__(256) void gemm_o(
        const signed char* __restrict__ aq, const signed char* __restrict__ wo,
        const double* __restrict__ ascale, const double* __restrict__ wscale_p,
        float* __restrict__ out) {
    gemm_core(aq, wo, ascale, *wscale_p, out, 1, 1.0f, blockIdx.x, blockIdx.y);
}

// ---------------- MFMA flash attention v11: qs=2 amortization + V in regs from L1 ---------
// v10 post-mortem: LDS pipe ~90% (24 b128-equiv/wave-tile x 1024 wave-tiles x 12cyc = 295K
// of 326K cyc). K+V fragment reads are FIXED per 16 q-rows -> double rows/wave (qs=2,
// 32 rows) to halve per-row LDS cost, and move V off LDS entirely:
//  - V frags held in REGISTERS (32 VGPR), loaded from fragment-tiled global planes
//    (1KB contiguous per f16x8 instr, v7-verified layout), prefetched ONE FULL TILE ahead
//    (issued after PV(t), consumed at PV(t+1)) -> L1 latency fully covered.
//  - 512 blocks, 2/CU sharing bh (same K/V addresses -> L1/L2 reuse); 8 waves/CU.
//  - Per tile/CU ledger: MFMA ~1860, LDS ~1730, L1 ~1540 cyc -> balanced, ideal 51us.
// Keeps v10 diet: exp2 builtin, cvt_pkrtz limb split, zero-quad init, setprio on MFMA.
#define KH_IDX(row, d8) (((row) * 8 + ((d8) ^ ((row) & 7))) * 8)       // halves

__global__ __launch_bounds__(256, 2) void attn_mfma(
        const unsigned short* __restrict__ qhg, const unsigned short* __restrict__ qlg,
        const unsigned short* __restrict__ khg, const unsigned short* __restrict__ klg,
        const unsigned short* __restrict__ vhg, const unsigned short* __restrict__ vlg,
        float* __restrict__ out) {
    __shared__ __align__(16) _Float16 KhL[32 * 64];
    __shared__ __align__(16) _Float16 KlL[32 * 64];
    __shared__ __align__(16) _Float16 PhL[4][32 * 36];   // pad-36 rows: <=2-way banks
    __shared__ __align__(16) _Float16 PlL[4][32 * 36];
    __shared__ float Lp[4][2][16][4];

    const int lin  = blockIdx.x;
    const int bh   = (lin & 7) * 4 + ((lin >> 3) & 3);   // co-resident blocks share bh
    const int qblk = lin >> 5;                           // [0,16), 128 q-rows each
    const int tid  = threadIdx.x;
    const int wave = tid >> 6, lane = tid & 63;
    const int l15  = lane & 15, quad = lane >> 4;
    const int qbase = qblk * 128 + wave * 32;

    // ---- Q fragments: direct f16x8 loads from separate limb planes ----
    f16x8 qh[2][2], qm[2][2];
    #pragma unroll
    for (int qs = 0; qs < 2; qs++) {
        #pragma unroll
        for (int c = 0; c < 2; c++) {
            size_t off = (((size_t)bh * SEQ + qbase + qs * 16 + l15) << 6) + c * 32 + quad * 8;
            qh[qs][c] = *(const f16x8*)(qhg + off);
            qm[qs][c] = *(const f16x8*)(qlg + off);
        }
    }

    floatx4 och[2][4] = {};   // [qs][nh] hi-scale PV acc
    floatx4 ocm[2][4] = {};   // [qs][nh] 2^-11-scale PV acc
    float lsum[2] = {0.f, 0.f};
    const floatx4 zf = {};    // shared zero quad for QK acc init

    const unsigned short* khb = khg + ((size_t)bh * SEQ << 6);   // [t][dh] plane
    const unsigned short* klb = klg + ((size_t)bh * SEQ << 6);
    const unsigned short* vhb = vhg + ((size_t)bh << 17);        // fragment-tiled plane
    const unsigned short* vlb = vlg + ((size_t)bh << 17);

    const int kk = tid >> 3, d8 = tid & 7;

    // prologue: prefetch K tile 0 into regs; V tile 0 fragments into regs
    uint4 kh_pf = *(const uint4*)(khb + ((size_t)kk << 6) + d8 * 8);
    uint4 kl_pf = *(const uint4*)(klb + ((size_t)kk << 6) + d8 * 8);
    f16x8 vfh[4], vfm[4];
    #pragma unroll
    for (int nh = 0; nh < 4; nh++) {
        size_t vo = ((size_t)(nh * 16 + l15) << 5) + quad * 8;
        vfh[nh] = *(const f16x8*)(vhb + vo);
        vfm[nh] = *(const f16x8*)(vlb + vo);
    }

    for (int t = 0; t < 64; t++) {
        BAR_LGKM();   // LDS reads from previous tile done (no vmcnt drain)

        *(uint4*)&KhL[KH_IDX(kk, d8)] = kh_pf;   // auto vmcnt wait on K prefetch regs only
        *(uint4*)&KlL[KH_IDX(kk, d8)] = kl_pf;

        if (t + 1 < 64) {   // prefetch K(t+1): full tile of latency tolerance
            kh_pf = *(const uint4*)(khb + ((size_t)((t + 1) * 32 + kk) << 6) + d8 * 8);
            kl_pf = *(const uint4*)(klb + ((size_t)((t + 1) * 32 + kk) << 6) + d8 * 8);
        }

        BAR_LGKM();   // staged K visible

        // K fragments (A-operand), direct f16x8 from LDS — amortized over 32 q-rows
        f16x8 kfh[2][2], kfl[2][2];
        #pragma unroll
        for (int ms = 0; ms < 2; ms++) {
            #pragma unroll
            for (int c = 0; c < 2; c++) {
                kfh[ms][c] = *(const f16x8*)&KhL[KH_IDX(ms * 16 + l15, c * 4 + quad)];
                kfl[ms][c] = *(const f16x8*)&KlL[KH_IDX(ms * 16 + l15, c * 4 + quad)];
            }
        }

        // QK MFMAs (24): 2 qs x 2 ms x 6
        __builtin_amdgcn_s_setprio(1);
        floatx4 ah[2][2], am[2][2];
        #pragma unroll
        for (int qs = 0; qs < 2; qs++) {
            #pragma unroll
            for (int ms = 0; ms < 2; ms++) {
                ah[qs][ms] = __builtin_amdgcn_mfma_f32_16x16x32_f16(kfh[ms][0], qh[qs][0], zf, 0, 0, 0);
                am[qs][ms] = __builtin_amdgcn_mfma_f32_16x16x32_f16(kfh[ms][0], qm[qs][0], zf, 0, 0, 0);
                am[qs][ms] = __builtin_amdgcn_mfma_f32_16x16x32_f16(kfl[ms][0], qh[qs][0], am[qs][ms], 0, 0, 0);
                ah[qs][ms] = __builtin_amdgcn_mfma_f32_16x16x32_f16(kfh[ms][1], qh[qs][1], ah[qs][ms], 0, 0, 0);
                am[qs][ms] = __builtin_amdgcn_mfma_f32_16x16x32_f16(kfh[ms][1], qm[qs][1], am[qs][ms], 0, 0, 0);
                am[qs][ms] = __builtin_amdgcn_mfma_f32_16x16x32_f16(kfl[ms][1], qh[qs][1], am[qs][ms], 0, 0, 0);
            }
        }
        __builtin_amdgcn_s_setprio(0);

        // softmax: p = exp2(s) -> P limb planes (cvt_pkrtz packed)
        #pragma unroll
        for (int qs = 0; qs < 2; qs++) {
            #pragma unroll
            for (int ms = 0; ms < 2; ms++) {
                float p0 = __builtin_amdgcn_exp2f(ah[qs][ms][0] + am[qs][ms][0] * 4.8828125e-4f);
                float p1 = __builtin_amdgcn_exp2f(ah[qs][ms][1] + am[qs][ms][1] * 4.8828125e-4f);
                float p2 = __builtin_amdgcn_exp2f(ah[qs][ms][2] + am[qs][ms][2] * 4.8828125e-4f);
                float p3 = __builtin_amdgcn_exp2f(ah[qs][ms][3] + am[qs][ms][3] * 4.8828125e-4f);
                lsum[qs] += (p0 + p1) + (p2 + p3);
                fp16x2 h01 = __builtin_amdgcn_cvt_pkrtz(p0, p1);
                fp16x2 h23 = __builtin_amdgcn_cvt_pkrtz(p2, p3);
                fp16x2 m01 = __builtin_amdgcn_cvt_pkrtz((p0 - (float)h01[0]) * 2048.0f,
                                                        (p1 - (float)h01[1]) * 2048.0f);
                fp16x2 m23 = __builtin_amdgcn_cvt_pkrtz((p2 - (float)h23[0]) * 2048.0f,
                                                        (p3 - (float)h23[1]) * 2048.0f);
                int poff = (qs * 16 + l15) * 36 + ms * 16 + quad * 4;
                *(uint2*)&PhL[wave][poff] = make_uint2(pk2u(h01), pk2u(h23));
                *(uint2*)&PlL[wave][poff] = make_uint2(pk2u(m01), pk2u(m23));
            }
        }
        WAIT_LGKM();   // P writes visible to own wave's cross-lane reads (vmcnt untouched)

        // PV MFMAs (24): V fragments already in regs (prefetched last iteration)
        __builtin_amdgcn_s_setprio(1);
        #pragma unroll
        for (int qs = 0; qs < 2; qs++) {
            f16x8 pfh = *(const f16x8*)&PhL[wave][(qs * 16 + l15) * 36 + quad * 8];
            f16x8 pfm = *(const f16x8*)&PlL[wave][(qs * 16 + l15) * 36 + quad * 8];
            #pragma unroll
            for (int nh = 0; nh < 4; nh++) {
                och[qs][nh] = __builtin_amdgcn_mfma_f32_16x16x32_f16(pfh, vfh[nh], och[qs][nh], 0, 0, 0);
                ocm[qs][nh] = __builtin_amdgcn_mfma_f32_16x16x32_f16(pfh, vfm[nh], ocm[qs][nh], 0, 0, 0);
                ocm[qs][nh] = __builtin_amdgcn_mfma_f32_16x16x32_f16(pfm, vfh[nh], ocm[qs][nh], 0, 0, 0);
            }
        }
        __builtin_amdgcn_s_setprio(0);

        // prefetch V(t+1) fragments from fragment-tiled global (1KB contiguous/instr);
        // consumed at PV(t+1): slack = barrier + K stage + QK + softmax (>>L2 latency)
        if (t + 1 < 64) {
            #pragma unroll
            for (int nh = 0; nh < 4; nh++) {
                size_t vo = ((size_t)((t + 1) * 64 + nh * 16 + l15) << 5) + quad * 8;
                vfh[nh] = *(const f16x8*)(vhb + vo);
                vfm[nh] = *(const f16x8*)(vlb + vo);
            }
        }
    }

    // ---- epilogue: merge l across quads, normalize, write ----
    Lp[wave][0][l15][quad] = lsum[0];
    Lp[wave][1][l15][quad] = lsum[1];
    WAIT_LGKM();

    int b = bh >> 4, h = bh & 15;
    #pragma unroll
    for (int qs = 0; qs < 2; qs++) {
        float linv[4];
        #pragma unroll
        for (int r = 0; r < 4; r++) {
            float4 lv = *(const float4*)&Lp[wave][qs][quad * 4 + r][0];
            linv[r] = 1.0f / (lv.x + lv.y + lv.z + lv.w);
        }
        #pragma unroll
        for (int nh = 0; nh < 4; nh++) {
            #pragma unroll
            for (int r = 0; r < 4; r++) {
                int token = b * SEQ + qbase + qs * 16 + quad * 4 + r;
                float val = (och[qs][nh][r] + ocm[qs][nh][r] * 4.8828125e-4f) * linv[r];
                out[(size_t)token * DM + h * 64 + nh * 16 + l15] = val;
            }
        }
    }
}

extern "C" void kernel_launch(void* const* d_in, const int* in_sizes, int n_in,
                              void* d_out, int out_size, void* d_ws, size_t ws_size,
                              hipStream_t stream) {
    const float* x       = (const float*)d_in[0];
    const float* context = (const float*)d_in[1];
    const float* Wq      = (const float*)d_in[2];
    const float* Wk      = (const float*)d_in[3];
    const float* Wv      = (const float*)d_in[4];
    const float* Wo      = (const float*)d_in[5];
    char* ws = (char*)d_ws;

    // workspace layout (~71.4 MB). Plane region at +21102592:
    //   Qh 8MB | Ql 8MB | Kh 8MB | Kl 8MB | Vh 8MB | Vl 8MB  (48 MB total)
    double* wscale   = (double*)(ws + 0);            // 4 doubles
    double* partial  = (double*)(ws + 4096);         // 256 doubles
    double* ascale_x = (double*)(ws + 8192);         // 8192 doubles (x then ctx)
    double* ascale_a = (double*)(ws + 73728);        // 4096 doubles
    signed char* wqb = (signed char*)(ws + 131072);          // 4 x 1 MB int8
    signed char* xq  = (signed char*)(ws + 4325376);         // 4 MB (cq follows)
    signed char* cq  = (signed char*)(ws + 8519680);         // 4 MB
    float* attn_out  = (float*)(ws + 4325376);               // aliases xq+cq region (16 MB)
    char* planes     = ws + 21102592;                        // 48 MB limb planes
    signed char* aq  = (signed char*)(ws + 21102592);        // aliases Q planes, used after attention

    unsigned short* qhg = (unsigned short*)planes;
    unsigned short* qlg = qhg + 4194304;
    unsigned short* khg = (unsigned short*)(planes + 16777216);
    unsigned short* klg = khg + 4194304;
    unsigned short* vhg = (unsigned short*)(planes + 33554432);
    unsigned short* vlg = vhg + 4194304;

    wsum1<<<dim3(64, 4), 256, 0, stream>>>(Wq, Wk, Wv, Wo, partial);
    wsum2<<<1, 64, 0, stream>>>(partial, wscale);
    wquant<<<dim3(1024, 4), 256, 0, stream>>>(Wq, Wk, Wv, Wo, wscale, wqb);
    aquant2<<<2 * NTOK, 256, 0, stream>>>(x, context, xq, ascale_x);

    gemm_qkv<<<dim3(24, 32), 256, 0, stream>>>(xq, cq, wqb, ascale_x, wscale, planes);

    attn_mfma<<<dim3(512), 256, 0, stream>>>(qhg, qlg, khg, klg, vhg, vlg, attn_out);

    aquant<<<NTOK, 256, 0, stream>>>(attn_out, aq, ascale_a);
    gemm_o<<<dim3(8, 32), 256, 0, stream>>>(aq, wqb + 3145728, ascale_a, wscale + 3, (float*)d_out);
}